// Round 3
// baseline (4211.480 us; speedup 1.0000x reference)
//
#include <hip/hip_runtime.h>
#include <hip/hip_bf16.h>

#define Nn 100000
#define Ee 1000000
#define INF_ 100
#define Hh 4
#define Dd 32
#define HD 128
#define Cc 47
#define HC 188
#define EPSV 1e-5f
#define SLOPE 0.2f

typedef __hip_bfloat16 bf16;

__device__ __forceinline__ float tof(bf16 v) { return __bfloat162float(v); }

// order-preserving float -> uint encoding (for atomicMax-based segment max)
__device__ __forceinline__ unsigned fenc(float f) {
    unsigned u = __float_as_uint(f);
    return (u & 0x80000000u) ? ~u : (u | 0x80000000u);
}
__device__ __forceinline__ float fdec(unsigned k) {
    unsigned u = (k & 0x80000000u) ? (k & 0x7FFFFFFFu) : ~k;
    return __uint_as_float(u);
}

// ---------------- dtype detect: 1 = bf16 buffers, 0 = fp32 buffers ----------------
__global__ void detect_dtype(const unsigned* __restrict__ x, int* __restrict__ flag) {
    if (blockIdx.x == 0 && threadIdx.x == 0) {
        int good = 0;
        for (int i = 0; i < 256; ++i) {
            unsigned lo = x[i] & 0xFFFFu;
            float v = __uint_as_float(lo << 16);
            float a = fabsf(v);
            if (a > 1e-4f && a < 10.f) good++;
        }
        *flag = (good >= 128) ? 1 : 0;
    }
}

// ---------------- converters to canonical bf16 ----------------
__global__ void cvt_x(const void* __restrict__ in, bf16* __restrict__ out, int n,
                      const int* __restrict__ flag) {
    int i = blockIdx.x * blockDim.x + threadIdx.x;
    if (i >= n) return;
    int isbf = *flag;
    float v = isbf ? tof(((const bf16*)in)[i]) : ((const float*)in)[i];
    out[i] = __float2bfloat16(v);
}

#define NPAR 23
struct CvtTab { const void* src[NPAR]; int off[NPAR + 1]; };

__global__ void cvt_params(CvtTab t, bf16* __restrict__ out, int total,
                           const int* __restrict__ flag) {
    int i = blockIdx.x * blockDim.x + threadIdx.x;
    if (i >= total) return;
    int isbf = *flag;
    int seg = 0;
    while (i >= t.off[seg + 1]) seg++;
    int j = i - t.off[seg];
    float v = isbf ? tof(((const bf16*)t.src[seg])[j]) : ((const float*)t.src[seg])[j];
    out[i] = __float2bfloat16(v);
}

__global__ void zero_u32(unsigned* __restrict__ p, int n) {
    int i = blockIdx.x * blockDim.x + threadIdx.x;
    if (i < n) p[i] = 0u;
}

// ---------------- GEMM: out[N,M] = A[N,K] @ W[K,M] + bias (all bf16 in) ----------------
template <typename TOUT>
__global__ void gemm_bias(const bf16* __restrict__ A, const bf16* __restrict__ W,
                          const bf16* __restrict__ bias, TOUT* __restrict__ out,
                          int K, int M) {
    __shared__ float Al[32 * 128];
    const int row0 = blockIdx.x * 32;
    const int tid = threadIdx.x;
    int rows = Nn - row0; if (rows > 32) rows = 32;
    for (int idx = tid; idx < rows * K; idx += 256) {
        int r = idx / K, c = idx - r * K;
        Al[r * K + c] = tof(A[(size_t)(row0 + r) * K + c]);
    }
    __syncthreads();
    for (int idx = tid; idx < rows * M; idx += 256) {
        int r = idx / M, c = idx - r * M;
        const float* a = &Al[r * K];
        float acc = tof(bias[c]);
        for (int k = 0; k < K; ++k)
            acc = fmaf(a[k], tof(W[k * M + c]), acc);
        TOUT* p = &out[(size_t)(row0 + r) * M + c];
        if constexpr (sizeof(TOUT) == 2) *p = __float2bfloat16(acc); else *p = acc;
    }
}

// residual copy for layer 1 (bf16 h -> fp32 accumulator)
__global__ void copy_b2f(const bf16* __restrict__ in, float* __restrict__ out, int n) {
    int i = blockIdx.x * blockDim.x + threadIdx.x;
    if (i < n) out[i] = tof(in[i]);
}

// ---------------- edge pass 1: logits + segment max ----------------
template <int DH, int M>
__global__ void edge_logits(const bf16* __restrict__ fs, const bf16* __restrict__ fd,
                            const int* __restrict__ src, const int* __restrict__ dst,
                            const bf16* __restrict__ attn, float* __restrict__ logits,
                            unsigned* __restrict__ menc) {
    int t = blockIdx.x * blockDim.x + threadIdx.x;
    if (t >= Ee * Hh) return;
    int e = t >> 2, h = t & 3;
    int s = src[e], d = dst[e];
    const bf16* ps = fs + (size_t)s * M + h * DH;
    const bf16* pd = fd + (size_t)d * M + h * DH;
    float acc = 0.f;
#pragma unroll
    for (int i = 0; i < DH; ++i) {
        float v = tof(ps[i]) + tof(pd[i]);
        v = v > 0.f ? v : v * SLOPE;
        acc = fmaf(v, tof(attn[h * DH + i]), acc);
    }
    logits[t] = acc;
    atomicMax(&menc[(size_t)d * Hh + h], fenc(acc));
}

// ---------------- edge pass 2: exp + segment sum ----------------
__global__ void edge_exp(const int* __restrict__ dst, const unsigned* __restrict__ menc,
                         float* __restrict__ logits, float* __restrict__ ssum) {
    int t = blockIdx.x * blockDim.x + threadIdx.x;
    if (t >= Ee * Hh) return;
    int e = t >> 2, h = t & 3;
    int d = dst[e];
    float m = fdec(menc[(size_t)d * Hh + h]);
    float ex = expf(logits[t] - m);
    logits[t] = ex;
    atomicAdd(&ssum[(size_t)d * Hh + h], ex);
}

// ---------------- edge pass 3: Obuf[dst] += alpha * fs[src] ----------------
// dst is sorted: accumulate locally while dst unchanged, flush on change.
template <int DH, int M>
__global__ void edge_aggregate(const bf16* __restrict__ fs, const int* __restrict__ src,
                               const int* __restrict__ dst, const float* __restrict__ ex,
                               const float* __restrict__ ssum, float* __restrict__ Ob) {
    const int ECH = 256;
    int c = blockIdx.y * 64 + threadIdx.x;
    if (c >= M) return;
    int h = c / DH;
    int e0 = blockIdx.x * ECH;
    int e1 = e0 + ECH; if (e1 > Ee) e1 = Ee;
    float acc = 0.f;
    int curd = dst[e0];
    for (int e = e0; e < e1; ++e) {
        int d = dst[e];
        if (d != curd) {
            atomicAdd(&Ob[(size_t)curd * M + c], acc);
            acc = 0.f; curd = d;
        }
        float alpha = ex[(size_t)e * Hh + h] / ssum[(size_t)d * Hh + h];
        acc = fmaf(alpha, tof(fs[(size_t)src[e] * M + c]), acc);
    }
    atomicAdd(&Ob[(size_t)curd * M + c], acc);
}

// ---------------- relu + per-column BN stats ----------------
__global__ void relu_stats(const float* __restrict__ in, bf16* __restrict__ hout,
                           float* __restrict__ sums) {
    int c = threadIdx.x;  // 128
    int r0 = blockIdx.x * 256;
    int r1 = r0 + 256; if (r1 > Nn) r1 = Nn;
    float s = 0.f, s2 = 0.f;
    for (int r = r0; r < r1; ++r) {
        float v = in[(size_t)r * HD + c];
        v = v > 0.f ? v : 0.f;
        hout[(size_t)r * HD + c] = __float2bfloat16(v);
        s += v; s2 += v * v;
    }
    atomicAdd(&sums[c], s);
    atomicAdd(&sums[HD + c], s2);
}

__global__ void bn_finalize(const float* __restrict__ sums, const bf16* __restrict__ g,
                            const bf16* __restrict__ be, float* __restrict__ ss) {
    int c = threadIdx.x;  // 128
    float mu = sums[c] * (1.f / Nn);
    float var = sums[HD + c] * (1.f / Nn) - mu * mu;
    float sc = tof(g[c]) * rsqrtf(var + EPSV);
    ss[c] = sc;
    ss[HD + c] = tof(be[c]) - mu * sc;
}

__global__ void bn_apply(bf16* __restrict__ h, const float* __restrict__ ss) {
    int i = blockIdx.x * blockDim.x + threadIdx.x;
    if (i >= Nn * HD) return;
    int c = i & (HD - 1);
    float v = fmaf(tof(h[i]), ss[c], ss[HD + c]);
    h[i] = __float2bfloat16(v > 0.f ? v : 0.f);
}

// ---------------- head-mean + log_softmax + dtype-adaptive out ----------------
__global__ void final_out(const float* __restrict__ Ob, void* __restrict__ out,
                          const int* __restrict__ flag) {
    int n = blockIdx.x;
    int c = threadIdx.x;  // 64 lanes, 47 active
    const float* row = Ob + (size_t)n * HC;
    float v = -1e30f;
    if (c < Cc)
        v = 0.25f * (row[c] + row[c + Cc] + row[c + 2 * Cc] + row[c + 3 * Cc]);
    float mx = v;
#pragma unroll
    for (int o = 1; o < 64; o <<= 1) mx = fmaxf(mx, __shfl_xor(mx, o));
    float ex = (c < Cc) ? expf(v - mx) : 0.f;
    float sm = ex;
#pragma unroll
    for (int o = 1; o < 64; o <<= 1) sm += __shfl_xor(sm, o);
    if (c < Cc) {
        float r = v - mx - logf(sm);
        if (*flag) ((bf16*)out)[(size_t)n * Cc + c] = __float2bfloat16(r);
        else       ((float*)out)[(size_t)n * Cc + c] = r;
    }
}

extern "C" void kernel_launch(void* const* d_in, const int* in_sizes, int n_in,
                              void* d_out, int out_size, void* d_ws, size_t ws_size,
                              hipStream_t stream) {
    (void)in_sizes; (void)n_in; (void)out_size; (void)ws_size;
    const void* x = d_in[0];
    const int* src = (const int*)d_in[1];
    const int* dst = (const int*)d_in[2];

    char* ws = (char*)d_ws;
    size_t off = 0;
    auto alloc = [&](size_t bytes) {
        void* p = ws + off;
        off += (bytes + 255) & ~(size_t)255;
        return p;
    };
    // xb (20 MB) aliases exb (16 MB): xb dead after layer-0 GEMMs.
    bf16* xb = (bf16*)alloc((size_t)Nn * INF_ * 2);
    float* exb = (float*)xb;
    bf16* fs = (bf16*)alloc((size_t)Nn * HC * 2);
    bf16* fd = (bf16*)alloc((size_t)Nn * HC * 2);
    float* Ob = (float*)alloc((size_t)Nn * HC * 4);
    bf16* hb = (bf16*)alloc((size_t)Nn * HD * 2);
    unsigned* menc = (unsigned*)alloc((size_t)Nn * Hh * 4);
    float* ssum = (float*)alloc((size_t)Nn * Hh * 4);
    float* bns = (float*)alloc(2 * HD * 4);
    float* bnss = (float*)alloc(2 * HD * 4);
    bf16* pb = (bf16*)alloc(160000 * 2);
    int* flag = (int*)alloc(256);

    // ---- param conversion table (d_in[3..25] -> bf16 arena) ----
    static const int psz[NPAR] = {
        INF_ * HD, HD, INF_ * HD, HD, Hh * Dd, INF_ * HD, HD,          // layer0
        HD * HD, HD, HD * HD, HD, Hh * Dd,                              // layer1
        HD * HC, HC, HD * HC, HC, Hh * Cc, HD * HC, HC,                 // layer2
        HD, HD, HD, HD };                                               // bn
    CvtTab tab;
    int tot = 0;
    for (int i = 0; i < NPAR; ++i) { tab.src[i] = d_in[3 + i]; tab.off[i] = tot; tot += psz[i]; }
    tab.off[NPAR] = tot;
    bf16* pp[NPAR];
    for (int i = 0; i < NPAR; ++i) pp[i] = pb + tab.off[i];
    const bf16 *Wsrc0 = pp[0], *bsrc0 = pp[1], *Wdst0 = pp[2], *bdst0 = pp[3],
               *attn0 = pp[4], *Wres0 = pp[5], *bres0 = pp[6],
               *Wsrc1 = pp[7], *bsrc1 = pp[8], *Wdst1 = pp[9], *bdst1 = pp[10],
               *attn1 = pp[11],
               *Wsrc2 = pp[12], *bsrc2 = pp[13], *Wdst2 = pp[14], *bdst2 = pp[15],
               *attn2 = pp[16], *Wres2 = pp[17], *bres2 = pp[18],
               *g0 = pp[19], *be0 = pp[20], *g1 = pp[21], *be1 = pp[22];

    const int gemmGrid = (Nn + 31) / 32;
    const int edgeGrid = (Ee * Hh + 255) / 256;
    dim3 aggGrid((Ee + 255) / 256, 2);
    dim3 aggGrid2((Ee + 255) / 256, 3);

    detect_dtype<<<1, 64, 0, stream>>>((const unsigned*)x, flag);
    cvt_x<<<(Nn * INF_ + 255) / 256, 256, 0, stream>>>(x, xb, Nn * INF_, flag);
    cvt_params<<<(tot + 255) / 256, 256, 0, stream>>>(tab, pb, tot, flag);

    auto zero_layer = [&]() {
        zero_u32<<<(Nn * Hh + 255) / 256, 256, 0, stream>>>(menc, Nn * Hh);
        zero_u32<<<(Nn * Hh + 255) / 256, 256, 0, stream>>>((unsigned*)ssum, Nn * Hh);
        zero_u32<<<1, 256, 0, stream>>>((unsigned*)bns, 2 * HD);
    };

    // ---------------- layer 0 ----------------
    gemm_bias<bf16><<<gemmGrid, 256, 0, stream>>>(xb, Wsrc0, bsrc0, fs, INF_, HD);
    gemm_bias<bf16><<<gemmGrid, 256, 0, stream>>>(xb, Wdst0, bdst0, fd, INF_, HD);
    gemm_bias<float><<<gemmGrid, 256, 0, stream>>>(xb, Wres0, bres0, Ob, INF_, HD);
    zero_layer();
    edge_logits<Dd, HD><<<edgeGrid, 256, 0, stream>>>(fs, fd, src, dst, attn0, exb, menc);
    edge_exp<<<edgeGrid, 256, 0, stream>>>(dst, menc, exb, ssum);
    edge_aggregate<Dd, HD><<<aggGrid, 64, 0, stream>>>(fs, src, dst, exb, ssum, Ob);
    relu_stats<<<(Nn + 255) / 256, 128, 0, stream>>>(Ob, hb, bns);
    bn_finalize<<<1, HD, 0, stream>>>(bns, g0, be0, bnss);
    bn_apply<<<(Nn * HD + 255) / 256, 256, 0, stream>>>(hb, bnss);

    // ---------------- layer 1 ----------------
    gemm_bias<bf16><<<gemmGrid, 256, 0, stream>>>(hb, Wsrc1, bsrc1, fs, HD, HD);
    gemm_bias<bf16><<<gemmGrid, 256, 0, stream>>>(hb, Wdst1, bdst1, fd, HD, HD);
    copy_b2f<<<(Nn * HD + 255) / 256, 256, 0, stream>>>(hb, Ob, Nn * HD);
    zero_layer();
    edge_logits<Dd, HD><<<edgeGrid, 256, 0, stream>>>(fs, fd, src, dst, attn1, exb, menc);
    edge_exp<<<edgeGrid, 256, 0, stream>>>(dst, menc, exb, ssum);
    edge_aggregate<Dd, HD><<<aggGrid, 64, 0, stream>>>(fs, src, dst, exb, ssum, Ob);
    relu_stats<<<(Nn + 255) / 256, 128, 0, stream>>>(Ob, hb, bns);
    bn_finalize<<<1, HD, 0, stream>>>(bns, g1, be1, bnss);
    bn_apply<<<(Nn * HD + 255) / 256, 256, 0, stream>>>(hb, bnss);

    // ---------------- layer 2 ----------------
    gemm_bias<bf16><<<gemmGrid, 256, 0, stream>>>(hb, Wsrc2, bsrc2, fs, HD, HC);
    gemm_bias<bf16><<<gemmGrid, 256, 0, stream>>>(hb, Wdst2, bdst2, fd, HD, HC);
    gemm_bias<float><<<gemmGrid, 256, 0, stream>>>(hb, Wres2, bres2, Ob, HD, HC);
    zero_u32<<<(Nn * Hh + 255) / 256, 256, 0, stream>>>(menc, Nn * Hh);
    zero_u32<<<(Nn * Hh + 255) / 256, 256, 0, stream>>>((unsigned*)ssum, Nn * Hh);
    edge_logits<Cc, HC><<<edgeGrid, 256, 0, stream>>>(fs, fd, src, dst, attn2, exb, menc);
    edge_exp<<<edgeGrid, 256, 0, stream>>>(dst, menc, exb, ssum);
    edge_aggregate<Cc, HC><<<aggGrid2, 64, 0, stream>>>(fs, src, dst, exb, ssum, Ob);
    final_out<<<Nn, 64, 0, stream>>>(Ob, d_out, flag);
}

// Round 4
// 1258.914 us; speedup vs baseline: 3.3453x; 3.3453x over previous
//
#include <hip/hip_runtime.h>
#include <hip/hip_bf16.h>

#define Nn 100000
#define Ee 1000000
#define INF_ 100
#define Hh 4
#define Dd 32
#define HD 128
#define Cc 47
#define HC 188
#define EPSV 1e-5f
#define SLOPE 0.2f

typedef __hip_bfloat16 bf16;
typedef __attribute__((ext_vector_type(8))) short short8;
typedef __attribute__((ext_vector_type(4))) float f32x4;

__device__ __forceinline__ float tof(bf16 v) { return __bfloat162float(v); }
__device__ __forceinline__ float b2f(unsigned short u) {
    return __uint_as_float((unsigned)u << 16);
}

// ---------------- dtype detect: 1 = bf16 buffers, 0 = fp32 buffers ----------------
__global__ void detect_dtype(const unsigned* __restrict__ x, int* __restrict__ flag) {
    if (blockIdx.x == 0 && threadIdx.x == 0) {
        int good = 0;
        for (int i = 0; i < 256; ++i) {
            unsigned lo = x[i] & 0xFFFFu;
            float v = __uint_as_float(lo << 16);
            float a = fabsf(v);
            if (a > 1e-4f && a < 10.f) good++;
        }
        *flag = (good >= 128) ? 1 : 0;
    }
}

// ---------------- converters to canonical bf16 ----------------
__global__ void cvt_x(const void* __restrict__ in, bf16* __restrict__ out, int n,
                      const int* __restrict__ flag) {
    int i = blockIdx.x * blockDim.x + threadIdx.x;
    if (i >= n) return;
    int isbf = *flag;
    float v = isbf ? tof(((const bf16*)in)[i]) : ((const float*)in)[i];
    out[i] = __float2bfloat16(v);
}

#define NPAR 23
struct CvtTab { const void* src[NPAR]; int off[NPAR + 1]; };

__global__ void cvt_params(CvtTab t, bf16* __restrict__ out, int total,
                           const int* __restrict__ flag) {
    int i = blockIdx.x * blockDim.x + threadIdx.x;
    if (i >= total) return;
    int isbf = *flag;
    int seg = 0;
    while (i >= t.off[seg + 1]) seg++;
    int j = i - t.off[seg];
    float v = isbf ? tof(((const bf16*)t.src[seg])[j]) : ((const float*)t.src[seg])[j];
    out[i] = __float2bfloat16(v);
}

__global__ void zero_u32(unsigned* __restrict__ p, int n) {
    int i = blockIdx.x * blockDim.x + threadIdx.x;
    if (i < n) p[i] = 0u;
}

// ---------------- CSR build: ptr[n] = lower_bound(dst, n); dst is sorted ----------------
__global__ void build_ptr(const int* __restrict__ dst, int* __restrict__ ptr) {
    int n = blockIdx.x * blockDim.x + threadIdx.x;
    if (n > Nn) return;
    if (n == Nn) { ptr[Nn] = Ee; return; }
    int lo = 0, hi = Ee;
    while (lo < hi) {
        int mid = (lo + hi) >> 1;
        if (dst[mid] < n) lo = mid + 1; else hi = mid;
    }
    ptr[n] = lo;
}

// ---------------- W[K][M] -> Wt[Mpad][128], zero padded ----------------
__global__ void prep_wt(const bf16* __restrict__ W, bf16* __restrict__ Wt,
                        int K, int M, int Mpad) {
    int i = blockIdx.x * blockDim.x + threadIdx.x;
    if (i >= Mpad * 128) return;
    int mm = i >> 7, k = i & 127;
    Wt[i] = (mm < M && k < K) ? W[k * M + mm] : __float2bfloat16(0.f);
}

// ---------------- MFMA GEMM: out[N,M] = A[N,KA] @ W + bias ----------------
// Wt is [Mpad][128] transposed+padded. 16 rows/block, 4 waves = 64 cols.
// A fragment: m=lane&15, k=quad*8+j.  C/D: col=lane&15, row=quad*4+reg.
template <int KA, typename TOUT>
__global__ __launch_bounds__(256) void gemm_mfma(const bf16* __restrict__ A,
                                                 const bf16* __restrict__ Wt,
                                                 const bf16* __restrict__ bias,
                                                 TOUT* __restrict__ out, int M) {
    __shared__ __align__(16) bf16 Al[16 * 136];  // +8 bf16 pad: bank-conflict free
    const int row0 = blockIdx.x * 16;            // N = 6250*16 exactly
    const int tid = threadIdx.x;
    if (KA == 128) {
        int r = tid >> 4, k = (tid & 15) * 8;
        *(int4*)&Al[r * 136 + k] = *(const int4*)&A[(size_t)(row0 + r) * 128 + k];
    } else {
        for (int idx = tid; idx < 16 * 128; idx += 256) {
            int r = idx >> 7, k = idx & 127;
            Al[r * 136 + k] = (k < KA) ? A[(size_t)(row0 + r) * KA + k]
                                       : __float2bfloat16(0.f);
        }
    }
    __syncthreads();
    const int wave = tid >> 6, lane = tid & 63;
    const int n16 = lane & 15, quad = lane >> 4;
    const int c0 = (blockIdx.y * 4 + wave) * 16;
    f32x4 acc = {0.f, 0.f, 0.f, 0.f};
    const bf16* wp = Wt + (size_t)(c0 + n16) * 128 + quad * 8;
    const bf16* ap = Al + n16 * 136 + quad * 8;
#pragma unroll
    for (int ks = 0; ks < 4; ++ks) {
        short8 af = *(const short8*)(ap + ks * 32);
        short8 bfr = *(const short8*)(wp + ks * 32);
        acc = __builtin_amdgcn_mfma_f32_16x16x32_bf16(af, bfr, acc, 0, 0, 0);
    }
    int c = c0 + n16;
    if (c < M) {
        float bb = tof(bias[c]);
#pragma unroll
        for (int i = 0; i < 4; ++i) {
            int row = row0 + quad * 4 + i;
            float v = acc[i] + bb;
            TOUT* p = &out[(size_t)row * M + c];
            if constexpr (sizeof(TOUT) == 2) *p = __float2bfloat16(v); else *p = v;
        }
    }
}

// ---------------- fused GATv2 edge kernel, M=128 (layers 0,1) ----------------
// One wave per dst node; online softmax; lane holds cols (2*lane, 2*lane+1),
// both in head lane>>4. RES_BF16: residual from resb (identity), else from Ob.
template <bool RES_BF16>
__global__ __launch_bounds__(256) void gat_fused_128(
    const bf16* __restrict__ fs, const bf16* __restrict__ fd,
    const int* __restrict__ srcI, const int* __restrict__ ptr,
    const bf16* __restrict__ attn, const bf16* __restrict__ resb,
    float* __restrict__ Ob) {
    const int wave = threadIdx.x >> 6, lane = threadIdx.x & 63;
    const int d = blockIdx.x * 4 + wave;
    if (d >= Nn) return;
    const int c0 = lane * 2;
    ushort2 aq = *(const ushort2*)&attn[c0];
    float a0 = b2f(aq.x), a1 = b2f(aq.y);
    ushort2 dq = *(const ushort2*)&fd[(size_t)d * HD + c0];
    float fd0 = b2f(dq.x), fd1 = b2f(dq.y);
    float m = -INFINITY, l = 0.f, O0 = 0.f, O1 = 0.f;
    const int e1 = ptr[d + 1];
    for (int e = ptr[d]; e < e1; ++e) {
        int s = srcI[e];
        ushort2 fq = *(const ushort2*)&fs[(size_t)s * HD + c0];
        float f0 = b2f(fq.x), f1 = b2f(fq.y);
        float t0 = f0 + fd0; t0 = t0 > 0.f ? t0 : t0 * SLOPE;
        float t1 = f1 + fd1; t1 = t1 > 0.f ? t1 : t1 * SLOPE;
        float p = fmaf(t0, a0, t1 * a1);
        p += __shfl_xor(p, 1); p += __shfl_xor(p, 2);
        p += __shfl_xor(p, 4); p += __shfl_xor(p, 8);
        float mn = fmaxf(m, p);
        float sc = __expf(m - mn);
        float pe = __expf(p - mn);
        l = fmaf(l, sc, pe);
        O0 = fmaf(O0, sc, pe * f0);
        O1 = fmaf(O1, sc, pe * f1);
        m = mn;
    }
    float r0, r1;
    if (RES_BF16) {
        ushort2 rq = *(const ushort2*)&resb[(size_t)d * HD + c0];
        r0 = b2f(rq.x); r1 = b2f(rq.y);
    } else {
        r0 = Ob[(size_t)d * HD + c0];
        r1 = Ob[(size_t)d * HD + c0 + 1];
    }
    float inv = l > 0.f ? 1.f / l : 0.f;
    Ob[(size_t)d * HD + c0]     = fmaf(O0, inv, r0);
    Ob[(size_t)d * HD + c0 + 1] = fmaf(O1, inv, r1);
}

// ---------------- fused GATv2 edge kernel, M=188 (layer 2) ----------------
// Lane holds cols lane, lane+64, lane+128(<188). Heads straddle lanes ->
// float4 head-partial butterfly reduce. Residual already in Ob.
__global__ __launch_bounds__(256) void gat_fused_188(
    const bf16* __restrict__ fs, const bf16* __restrict__ fd,
    const int* __restrict__ srcI, const int* __restrict__ ptr,
    const bf16* __restrict__ attn, float* __restrict__ Ob) {
    const int wave = threadIdx.x >> 6, lane = threadIdx.x & 63;
    const int d = blockIdx.x * 4 + wave;
    if (d >= Nn) return;
    const int cA = lane, cB = lane + 64, cC = lane + 128;
    const bool v2 = (cC < HC);
    const int h0 = (cA < 47) ? 0 : 1;
    const int h1 = (cB < 94) ? 1 : 2;
    const int h2 = (cC < 141) ? 2 : 3;
    float a0 = b2f(*(const unsigned short*)&attn[cA]);
    float a1 = b2f(*(const unsigned short*)&attn[cB]);
    float a2 = v2 ? b2f(*(const unsigned short*)&attn[cC]) : 0.f;
    const bf16* fdr = fd + (size_t)d * HC;
    float fd0 = b2f(*(const unsigned short*)&fdr[cA]);
    float fd1 = b2f(*(const unsigned short*)&fdr[cB]);
    float fd2 = v2 ? b2f(*(const unsigned short*)&fdr[cC]) : 0.f;
    float m4[4] = {-INFINITY, -INFINITY, -INFINITY, -INFINITY};
    float l4[4] = {0.f, 0.f, 0.f, 0.f};
    float O0 = 0.f, O1 = 0.f, O2 = 0.f;
    const int e1 = ptr[d + 1];
    for (int e = ptr[d]; e < e1; ++e) {
        int s = srcI[e];
        const bf16* fr = fs + (size_t)s * HC;
        float f0 = b2f(*(const unsigned short*)&fr[cA]);
        float f1 = b2f(*(const unsigned short*)&fr[cB]);
        float f2 = v2 ? b2f(*(const unsigned short*)&fr[cC]) : 0.f;
        float t0 = f0 + fd0; t0 = t0 > 0.f ? t0 : t0 * SLOPE;
        float t1 = f1 + fd1; t1 = t1 > 0.f ? t1 : t1 * SLOPE;
        float t2 = f2 + fd2; t2 = t2 > 0.f ? t2 : t2 * SLOPE;
        float q0 = t0 * a0, q1 = t1 * a1, q2 = t2 * a2;
        float p4[4];
        p4[0] = (h0 == 0) ? q0 : 0.f;
        p4[1] = ((h0 == 1) ? q0 : 0.f) + ((h1 == 1) ? q1 : 0.f);
        p4[2] = ((h1 == 2) ? q1 : 0.f) + ((h2 == 2 && v2) ? q2 : 0.f);
        p4[3] = (h2 == 3 && v2) ? q2 : 0.f;
#pragma unroll
        for (int off = 1; off < 64; off <<= 1) {
            p4[0] += __shfl_xor(p4[0], off);
            p4[1] += __shfl_xor(p4[1], off);
            p4[2] += __shfl_xor(p4[2], off);
            p4[3] += __shfl_xor(p4[3], off);
        }
        float sc4[4], pe4[4];
#pragma unroll
        for (int h = 0; h < 4; ++h) {
            float mn = fmaxf(m4[h], p4[h]);
            sc4[h] = __expf(m4[h] - mn);
            pe4[h] = __expf(p4[h] - mn);
            l4[h] = fmaf(l4[h], sc4[h], pe4[h]);
            m4[h] = mn;
        }
        float s0 = (h0 == 0) ? sc4[0] : sc4[1], p0 = (h0 == 0) ? pe4[0] : pe4[1];
        float s1 = (h1 == 1) ? sc4[1] : sc4[2], p1 = (h1 == 1) ? pe4[1] : pe4[2];
        float s2 = (h2 == 2) ? sc4[2] : sc4[3], p2 = (h2 == 2) ? pe4[2] : pe4[3];
        O0 = fmaf(O0, s0, p0 * f0);
        O1 = fmaf(O1, s1, p1 * f1);
        O2 = fmaf(O2, s2, p2 * f2);
    }
    float inv4[4];
#pragma unroll
    for (int h = 0; h < 4; ++h) inv4[h] = l4[h] > 0.f ? 1.f / l4[h] : 0.f;
    float* orow = Ob + (size_t)d * HC;
    orow[cA] = fmaf(O0, (h0 == 0) ? inv4[0] : inv4[1], orow[cA]);
    orow[cB] = fmaf(O1, (h1 == 1) ? inv4[1] : inv4[2], orow[cB]);
    if (v2) orow[cC] = fmaf(O2, (h2 == 2) ? inv4[2] : inv4[3], orow[cC]);
}

// ---------------- relu + per-column BN stats ----------------
__global__ void relu_stats(const float* __restrict__ in, bf16* __restrict__ hout,
                           float* __restrict__ sums) {
    int c = threadIdx.x;  // 128
    int r0 = blockIdx.x * 256;
    int r1 = r0 + 256; if (r1 > Nn) r1 = Nn;
    float s = 0.f, s2 = 0.f;
    for (int r = r0; r < r1; ++r) {
        float v = in[(size_t)r * HD + c];
        v = v > 0.f ? v : 0.f;
        hout[(size_t)r * HD + c] = __float2bfloat16(v);
        s += v; s2 += v * v;
    }
    atomicAdd(&sums[c], s);
    atomicAdd(&sums[HD + c], s2);
}

__global__ void bn_finalize(const float* __restrict__ sums, const bf16* __restrict__ g,
                            const bf16* __restrict__ be, float* __restrict__ ss) {
    int c = threadIdx.x;  // 128
    float mu = sums[c] * (1.f / Nn);
    float var = sums[HD + c] * (1.f / Nn) - mu * mu;
    float sc = tof(g[c]) * rsqrtf(var + EPSV);
    ss[c] = sc;
    ss[HD + c] = tof(be[c]) - mu * sc;
}

__global__ void bn_apply(bf16* __restrict__ h, const float* __restrict__ ss) {
    int i = blockIdx.x * blockDim.x + threadIdx.x;
    if (i >= Nn * HD) return;
    int c = i & (HD - 1);
    float v = fmaf(tof(h[i]), ss[c], ss[HD + c]);
    h[i] = __float2bfloat16(v > 0.f ? v : 0.f);
}

// ---------------- head-mean + log_softmax + dtype-adaptive out ----------------
__global__ void final_out(const float* __restrict__ Ob, void* __restrict__ out,
                          const int* __restrict__ flag) {
    int n = blockIdx.x;
    int c = threadIdx.x;  // 64 lanes, 47 active
    const float* row = Ob + (size_t)n * HC;
    float v = -1e30f;
    if (c < Cc)
        v = 0.25f * (row[c] + row[c + Cc] + row[c + 2 * Cc] + row[c + 3 * Cc]);
    float mx = v;
#pragma unroll
    for (int o = 1; o < 64; o <<= 1) mx = fmaxf(mx, __shfl_xor(mx, o));
    float ex = (c < Cc) ? expf(v - mx) : 0.f;
    float sm = ex;
#pragma unroll
    for (int o = 1; o < 64; o <<= 1) sm += __shfl_xor(sm, o);
    if (c < Cc) {
        float r = v - mx - logf(sm);
        if (*flag) ((bf16*)out)[(size_t)n * Cc + c] = __float2bfloat16(r);
        else       ((float*)out)[(size_t)n * Cc + c] = r;
    }
}

extern "C" void kernel_launch(void* const* d_in, const int* in_sizes, int n_in,
                              void* d_out, int out_size, void* d_ws, size_t ws_size,
                              hipStream_t stream) {
    (void)in_sizes; (void)n_in; (void)out_size; (void)ws_size;
    const void* x = d_in[0];
    const int* src = (const int*)d_in[1];
    const int* dst = (const int*)d_in[2];

    char* ws = (char*)d_ws;
    size_t off = 0;
    auto alloc = [&](size_t bytes) {
        void* p = ws + off;
        off += (bytes + 255) & ~(size_t)255;
        return p;
    };
    bf16* xb = (bf16*)alloc((size_t)Nn * INF_ * 2);   // 20 MB
    bf16* fs = (bf16*)alloc((size_t)Nn * HC * 2);     // 37.6 MB
    bf16* fd = (bf16*)alloc((size_t)Nn * HC * 2);     // 37.6 MB
    float* Ob = (float*)alloc((size_t)Nn * HC * 4);   // 75.2 MB
    bf16* hb = (bf16*)alloc((size_t)Nn * HD * 2);     // 25.6 MB
    int* ptr = (int*)alloc((Nn + 1) * 4);             // 400 KB
    bf16* wtb = (bf16*)alloc(8 * 192 * 128 * 2);      // 393 KB
    float* bns = (float*)alloc(2 * HD * 4);
    float* bnss = (float*)alloc(2 * HD * 4);
    bf16* pb = (bf16*)alloc(160000 * 2);
    int* flag = (int*)alloc(256);

    // ---- param conversion table (d_in[3..25] -> bf16 arena) ----
    static const int psz[NPAR] = {
        INF_ * HD, HD, INF_ * HD, HD, Hh * Dd, INF_ * HD, HD,
        HD * HD, HD, HD * HD, HD, Hh * Dd,
        HD * HC, HC, HD * HC, HC, Hh * Cc, HD * HC, HC,
        HD, HD, HD, HD };
    CvtTab tab;
    int tot = 0;
    for (int i = 0; i < NPAR; ++i) { tab.src[i] = d_in[3 + i]; tab.off[i] = tot; tot += psz[i]; }
    tab.off[NPAR] = tot;
    bf16* pp[NPAR];
    for (int i = 0; i < NPAR; ++i) pp[i] = pb + tab.off[i];
    const bf16 *Wsrc0 = pp[0], *bsrc0 = pp[1], *Wdst0 = pp[2], *bdst0 = pp[3],
               *attn0 = pp[4], *Wres0 = pp[5], *bres0 = pp[6],
               *Wsrc1 = pp[7], *bsrc1 = pp[8], *Wdst1 = pp[9], *bdst1 = pp[10],
               *attn1 = pp[11],
               *Wsrc2 = pp[12], *bsrc2 = pp[13], *Wdst2 = pp[14], *bdst2 = pp[15],
               *attn2 = pp[16], *Wres2 = pp[17], *bres2 = pp[18],
               *g0 = pp[19], *be0 = pp[20], *g1 = pp[21], *be1 = pp[22];
    (void)Wsrc0; (void)Wdst0; (void)Wres0; (void)Wsrc1; (void)Wdst1;
    (void)Wsrc2; (void)Wdst2; (void)Wres2;

    bf16* wt[8];
    for (int i = 0; i < 8; ++i) wt[i] = wtb + i * 192 * 128;

    detect_dtype<<<1, 64, 0, stream>>>((const unsigned*)x, flag);
    cvt_x<<<(Nn * INF_ + 255) / 256, 256, 0, stream>>>(x, xb, Nn * INF_, flag);
    cvt_params<<<(tot + 255) / 256, 256, 0, stream>>>(tab, pb, tot, flag);
    build_ptr<<<(Nn + 256) / 256, 256, 0, stream>>>(dst, ptr);

    // transposed+padded weights (after cvt_params)
    const int wgK[8] = {INF_, INF_, INF_, HD, HD, HD, HD, HD};
    const int wgM[8] = {HD, HD, HD, HD, HD, HC, HC, HC};
    const bf16* wsrc[8] = {pp[0], pp[2], pp[5], pp[7], pp[9], pp[12], pp[14], pp[17]};
    for (int i = 0; i < 8; ++i) {
        int mp = (wgM[i] == HD) ? 128 : 192;
        prep_wt<<<(mp * 128 + 255) / 256, 256, 0, stream>>>(wsrc[i], wt[i], wgK[i], wgM[i], mp);
    }

    const dim3 g128(6250, 2), g188(6250, 3);
    const int fusedGrid = (Nn + 3) / 4;

    // ---------------- layer 0 ----------------
    gemm_mfma<INF_, bf16><<<g128, 256, 0, stream>>>(xb, wt[0], bsrc0, fs, HD);
    gemm_mfma<INF_, bf16><<<g128, 256, 0, stream>>>(xb, wt[1], bdst0, fd, HD);
    gemm_mfma<INF_, float><<<g128, 256, 0, stream>>>(xb, wt[2], bres0, Ob, HD);
    zero_u32<<<1, 256, 0, stream>>>((unsigned*)bns, 2 * HD);
    gat_fused_128<false><<<fusedGrid, 256, 0, stream>>>(fs, fd, src, ptr, attn0, nullptr, Ob);
    relu_stats<<<(Nn + 255) / 256, 128, 0, stream>>>(Ob, hb, bns);
    bn_finalize<<<1, HD, 0, stream>>>(bns, g0, be0, bnss);
    bn_apply<<<(Nn * HD + 255) / 256, 256, 0, stream>>>(hb, bnss);

    // ---------------- layer 1 ----------------
    gemm_mfma<HD, bf16><<<g128, 256, 0, stream>>>(hb, wt[3], bsrc1, fs, HD);
    gemm_mfma<HD, bf16><<<g128, 256, 0, stream>>>(hb, wt[4], bdst1, fd, HD);
    zero_u32<<<1, 256, 0, stream>>>((unsigned*)bns, 2 * HD);
    gat_fused_128<true><<<fusedGrid, 256, 0, stream>>>(fs, fd, src, ptr, attn1, hb, Ob);
    relu_stats<<<(Nn + 255) / 256, 128, 0, stream>>>(Ob, hb, bns);
    bn_finalize<<<1, HD, 0, stream>>>(bns, g1, be1, bnss);
    bn_apply<<<(Nn * HD + 255) / 256, 256, 0, stream>>>(hb, bnss);

    // ---------------- layer 2 ----------------
    gemm_mfma<HD, bf16><<<g188, 256, 0, stream>>>(hb, wt[5], bsrc2, fs, HC);
    gemm_mfma<HD, bf16><<<g188, 256, 0, stream>>>(hb, wt[6], bdst2, fd, HC);
    gemm_mfma<HD, float><<<g188, 256, 0, stream>>>(hb, wt[7], bres2, Ob, HC);
    gat_fused_188<<<fusedGrid, 256, 0, stream>>>(fs, fd, src, ptr, attn2, Ob);
    final_out<<<Nn, 64, 0, stream>>>(Ob, d_out, flag);
}

// Round 5
// 1080.450 us; speedup vs baseline: 3.8979x; 1.1652x over previous
//
#include <hip/hip_runtime.h>
#include <hip/hip_bf16.h>

#define Nn 100000
#define Ee 1000000
#define INF_ 100
#define Hh 4
#define Dd 32
#define HD 128
#define Cc 47
#define HC 188
#define EPSV 1e-5f
#define SLOPE 0.2f

typedef __hip_bfloat16 bf16;
typedef __attribute__((ext_vector_type(8))) short short8;
typedef __attribute__((ext_vector_type(4))) float f32x4;

__device__ __forceinline__ float tof(bf16 v) { return __bfloat162float(v); }
__device__ __forceinline__ float b2f(unsigned short u) {
    return __uint_as_float((unsigned)u << 16);
}
__device__ __forceinline__ float ldb(const bf16* p) {
    return b2f(*(const unsigned short*)p);
}

// ---------------- dtype detect: 1 = bf16 buffers, 0 = fp32 buffers ----------------
__global__ void detect_dtype(const unsigned* __restrict__ x, int* __restrict__ flag) {
    if (blockIdx.x == 0 && threadIdx.x == 0) {
        int good = 0;
        for (int i = 0; i < 256; ++i) {
            unsigned lo = x[i] & 0xFFFFu;
            float v = __uint_as_float(lo << 16);
            float a = fabsf(v);
            if (a > 1e-4f && a < 10.f) good++;
        }
        *flag = (good >= 128) ? 1 : 0;
    }
}

__device__ __forceinline__ float ld_any(const void* p, int i, int isbf) {
    return isbf ? tof(((const bf16*)p)[i]) : ((const float*)p)[i];
}

// ---------------- x -> canonical bf16 ----------------
__global__ void cvt_x(const void* __restrict__ in, bf16* __restrict__ out, int n,
                      const int* __restrict__ flag) {
    int i = blockIdx.x * blockDim.x + threadIdx.x;
    if (i >= n) return;
    out[i] = __float2bfloat16(ld_any(in, i, *flag));
}

// ---------------- small params (biases/attn/bn) -> canonical bf16 ----------------
#define NSP 15
struct CvtTab { const void* src[NSP]; int off[NSP + 1]; };

__global__ void cvt_params(CvtTab t, bf16* __restrict__ out, int total,
                           const int* __restrict__ flag) {
    int i = blockIdx.x * blockDim.x + threadIdx.x;
    if (i >= total) return;
    int isbf = *flag;
    int seg = 0;
    while (i >= t.off[seg + 1]) seg++;
    out[i] = __float2bfloat16(ld_any(t.src[seg], i - t.off[seg], isbf));
}

// ---------------- all 8 weight mats -> packed transposed Wt[1280][128] ----------------
#define WROWS 1280
struct PrepTab { const void* src[8]; int row0[8]; int K[8]; int M[8]; int MP[8]; };

__global__ void prep_all(PrepTab t, bf16* __restrict__ wtb, const int* __restrict__ flag) {
    int i = blockIdx.x * blockDim.x + threadIdx.x;
    if (i >= WROWS * 128) return;
    int row = i >> 7, k = i & 127;
    int isbf = *flag;
    float v = 0.f;
#pragma unroll
    for (int q = 0; q < 8; ++q) {
        if (row >= t.row0[q] && row < t.row0[q] + t.MP[q]) {
            int m = row - t.row0[q];
            if (m < t.M[q] && k < t.K[q])
                v = ld_any(t.src[q], k * t.M[q] + m, isbf);
        }
    }
    wtb[i] = __float2bfloat16(v);
}

__global__ void zero_u32(unsigned* __restrict__ p, int n) {
    int i = blockIdx.x * blockDim.x + threadIdx.x;
    if (i < n) p[i] = 0u;
}

// ---------------- CSR build: ptr[n] = lower_bound(dst, n); dst is sorted ----------------
__global__ void build_ptr(const int* __restrict__ dst, int* __restrict__ ptr) {
    int n = blockIdx.x * blockDim.x + threadIdx.x;
    if (n > Nn) return;
    if (n == Nn) { ptr[Nn] = Ee; return; }
    int lo = 0, hi = Ee;
    while (lo < hi) {
        int mid = (lo + hi) >> 1;
        if (dst[mid] < n) lo = mid + 1; else hi = mid;
    }
    ptr[n] = lo;
}

// ---------------- merged MFMA GEMM: NOUT outputs share A ----------------
// Wt packed [NOUT*MP(+pad)][128]; block = 16 rows x 128 cols (2 tiles/wave).
// A frag: m=lane&15, k=quad*8+j.  C/D: col=lane&15, row=quad*4+reg.
template <int KA, int MP, int NOUT, bool OUT2F>
__global__ __launch_bounds__(256) void gemm_multi(
    const bf16* __restrict__ A, const bf16* __restrict__ Wt,
    const bf16* __restrict__ b0, const bf16* __restrict__ b1,
    const bf16* __restrict__ b2,
    void* __restrict__ o0, void* __restrict__ o1, void* __restrict__ o2, int MR) {
    __shared__ __align__(16) bf16 Al[16 * 136];
    const int row0 = blockIdx.x * 16;  // N = 6250*16 exactly
    const int tid = threadIdx.x;
    if (KA == 128) {
        int r = tid >> 4, k = (tid & 15) * 8;
        *(int4*)&Al[r * 136 + k] = *(const int4*)&A[(size_t)(row0 + r) * 128 + k];
    } else {
        for (int idx = tid; idx < 16 * 128; idx += 256) {
            int r = idx >> 7, k = idx & 127;
            Al[r * 136 + k] = (k < KA) ? A[(size_t)(row0 + r) * KA + k]
                                       : __float2bfloat16(0.f);
        }
    }
    __syncthreads();
    const int wave = tid >> 6, lane = tid & 63;
    const int n16 = lane & 15, quad = lane >> 4;
    const int gbase = blockIdx.y * 128 + wave * 16 + n16;
    f32x4 acc0 = {0.f, 0.f, 0.f, 0.f}, acc1 = {0.f, 0.f, 0.f, 0.f};
    const bf16* wp0 = Wt + (size_t)gbase * 128 + quad * 8;
    const bf16* wp1 = wp0 + (size_t)64 * 128;
    const bf16* ap = Al + n16 * 136 + quad * 8;
#pragma unroll
    for (int ks = 0; ks < 4; ++ks) {
        short8 af = *(const short8*)(ap + ks * 32);
        acc0 = __builtin_amdgcn_mfma_f32_16x16x32_bf16(af, *(const short8*)(wp0 + ks * 32), acc0, 0, 0, 0);
        acc1 = __builtin_amdgcn_mfma_f32_16x16x32_bf16(af, *(const short8*)(wp1 + ks * 32), acc1, 0, 0, 0);
    }
#pragma unroll
    for (int tt = 0; tt < 2; ++tt) {
        int g = gbase + tt * 64;
        if (g >= NOUT * MP) continue;
        int oi = g / MP, lc = g - oi * MP;
        if (lc >= MR) continue;
        const bf16* bp = (oi == 0) ? b0 : (oi == 1) ? b1 : b2;
        float bb = tof(bp[lc]);
        const f32x4& a = tt ? acc1 : acc0;
        if (OUT2F && oi == 2) {
            float* o = (float*)o2;
#pragma unroll
            for (int i = 0; i < 4; ++i)
                o[(size_t)(row0 + quad * 4 + i) * MR + lc] = a[i] + bb;
        } else {
            bf16* o = (bf16*)((oi == 0) ? o0 : (oi == 1) ? o1 : o2);
#pragma unroll
            for (int i = 0; i < 4; ++i)
                o[(size_t)(row0 + quad * 4 + i) * MR + lc] = __float2bfloat16(a[i] + bb);
        }
    }
}

// ---------------- fused GATv2 edge kernel, M=128 (layers 0,1) ----------------
// One wave per dst; lane holds cols (2*lane, 2*lane+1), head = lane>>4;
// 16-lane-group butterfly. RES_BF16: residual from resb, else Ob already holds it.
template <bool RES_BF16>
__global__ __launch_bounds__(256) void gat_fused_128(
    const bf16* __restrict__ fs, const bf16* __restrict__ fd,
    const int* __restrict__ srcI, const int* __restrict__ ptr,
    const bf16* __restrict__ attn, const bf16* __restrict__ resb,
    float* __restrict__ Ob) {
    const int wave = threadIdx.x >> 6, lane = threadIdx.x & 63;
    const int d = blockIdx.x * 4 + wave;
    if (d >= Nn) return;
    const int c0 = lane * 2;
    ushort2 aq = *(const ushort2*)&attn[c0];
    float a0 = b2f(aq.x), a1 = b2f(aq.y);
    ushort2 dq = *(const ushort2*)&fd[(size_t)d * HD + c0];
    float fd0 = b2f(dq.x), fd1 = b2f(dq.y);
    float m = -INFINITY, l = 0.f, O0 = 0.f, O1 = 0.f;
    const int e1 = ptr[d + 1];
    for (int e = ptr[d]; e < e1; ++e) {
        int s = srcI[e];
        ushort2 fq = *(const ushort2*)&fs[(size_t)s * HD + c0];
        float f0 = b2f(fq.x), f1 = b2f(fq.y);
        float t0 = f0 + fd0; t0 = fmaxf(t0, t0 * SLOPE);
        float t1 = f1 + fd1; t1 = fmaxf(t1, t1 * SLOPE);
        float p = fmaf(t0, a0, t1 * a1);
        p += __shfl_xor(p, 1); p += __shfl_xor(p, 2);
        p += __shfl_xor(p, 4); p += __shfl_xor(p, 8);
        float mn = fmaxf(m, p);
        float sc = __expf(m - mn);
        float pe = __expf(p - mn);
        l = fmaf(l, sc, pe);
        O0 = fmaf(O0, sc, pe * f0);
        O1 = fmaf(O1, sc, pe * f1);
        m = mn;
    }
    float r0, r1;
    if (RES_BF16) {
        ushort2 rq = *(const ushort2*)&resb[(size_t)d * HD + c0];
        r0 = b2f(rq.x); r1 = b2f(rq.y);
    } else {
        r0 = Ob[(size_t)d * HD + c0];
        r1 = Ob[(size_t)d * HD + c0 + 1];
    }
    float inv = l > 0.f ? 1.f / l : 0.f;
    Ob[(size_t)d * HD + c0]     = fmaf(O0, inv, r0);
    Ob[(size_t)d * HD + c0 + 1] = fmaf(O1, inv, r1);
}

// ---------------- fused GATv2 edge kernel, M=188 (layer 2) ----------------
// Head-per-lane-group: lane = 16*h + j owns cols h*47 + {j, j+16, j+32 (j<15)}.
// Butterfly within 16-lane group; each lane tracks ONE head's online softmax.
__global__ __launch_bounds__(256) void gat_fused_188(
    const bf16* __restrict__ fs, const bf16* __restrict__ fd,
    const int* __restrict__ srcI, const int* __restrict__ ptr,
    const bf16* __restrict__ attn, float* __restrict__ Ob) {
    const int wave = threadIdx.x >> 6, lane = threadIdx.x & 63;
    const int d = blockIdx.x * 4 + wave;
    if (d >= Nn) return;
    const int h = lane >> 4, j = lane & 15;
    const int c0 = h * Cc + j;        // always valid; c0+16 valid; c0+32 iff j<15
    const bool v2 = (j < 15);
    float a0 = ldb(&attn[c0]);
    float a1 = ldb(&attn[c0 + 16]);
    float a2 = v2 ? ldb(&attn[c0 + 32]) : 0.f;
    const bf16* fdr = fd + (size_t)d * HC;
    float fd0 = ldb(&fdr[c0]);
    float fd1 = ldb(&fdr[c0 + 16]);
    float fd2 = v2 ? ldb(&fdr[c0 + 32]) : 0.f;
    float m = -INFINITY, l = 0.f, O0 = 0.f, O1 = 0.f, O2 = 0.f;
    const int e1 = ptr[d + 1];
    for (int e = ptr[d]; e < e1; ++e) {
        int s = srcI[e];
        const bf16* fr = fs + (size_t)s * HC;
        float f0 = ldb(&fr[c0]);
        float f1 = ldb(&fr[c0 + 16]);
        float f2 = v2 ? ldb(&fr[c0 + 32]) : 0.f;
        float t0 = f0 + fd0; t0 = fmaxf(t0, t0 * SLOPE);
        float t1 = f1 + fd1; t1 = fmaxf(t1, t1 * SLOPE);
        float t2 = f2 + fd2; t2 = fmaxf(t2, t2 * SLOPE);
        float p = fmaf(t0, a0, fmaf(t1, a1, t2 * a2));  // a2=0 masks invalid
        p += __shfl_xor(p, 1); p += __shfl_xor(p, 2);
        p += __shfl_xor(p, 4); p += __shfl_xor(p, 8);
        float mn = fmaxf(m, p);
        float sc = __expf(m - mn);
        float pe = __expf(p - mn);
        l = fmaf(l, sc, pe);
        O0 = fmaf(O0, sc, pe * f0);
        O1 = fmaf(O1, sc, pe * f1);
        O2 = fmaf(O2, sc, pe * f2);
        m = mn;
    }
    float inv = l > 0.f ? 1.f / l : 0.f;
    float* orow = Ob + (size_t)d * HC;
    orow[c0]      += O0 * inv;
    orow[c0 + 16] += O1 * inv;
    if (v2) orow[c0 + 32] += O2 * inv;
}

// ---------------- relu + per-column BN stats ----------------
__global__ void relu_stats(const float* __restrict__ in, bf16* __restrict__ hout,
                           float* __restrict__ sums) {
    int c = threadIdx.x;  // 128
    int r0 = blockIdx.x * 256;
    int r1 = r0 + 256; if (r1 > Nn) r1 = Nn;
    float s = 0.f, s2 = 0.f;
    for (int r = r0; r < r1; ++r) {
        float v = in[(size_t)r * HD + c];
        v = v > 0.f ? v : 0.f;
        hout[(size_t)r * HD + c] = __float2bfloat16(v);
        s += v; s2 += v * v;
    }
    atomicAdd(&sums[c], s);
    atomicAdd(&sums[HD + c], s2);
}

__global__ void bn_finalize(const float* __restrict__ sums, const bf16* __restrict__ g,
                            const bf16* __restrict__ be, float* __restrict__ ss) {
    int c = threadIdx.x;  // 128
    float mu = sums[c] * (1.f / Nn);
    float var = sums[HD + c] * (1.f / Nn) - mu * mu;
    float sc = tof(g[c]) * rsqrtf(var + EPSV);
    ss[c] = sc;
    ss[HD + c] = tof(be[c]) - mu * sc;
}

__global__ void bn_apply(bf16* __restrict__ h, const float* __restrict__ ss) {
    int i = blockIdx.x * blockDim.x + threadIdx.x;
    if (i >= Nn * HD) return;
    int c = i & (HD - 1);
    float v = fmaf(tof(h[i]), ss[c], ss[HD + c]);
    h[i] = __float2bfloat16(v > 0.f ? v : 0.f);
}

// ---------------- head-mean + log_softmax + dtype-adaptive out ----------------
__global__ void final_out(const float* __restrict__ Ob, void* __restrict__ out,
                          const int* __restrict__ flag) {
    int n = blockIdx.x;
    int c = threadIdx.x;  // 64 lanes, 47 active
    const float* row = Ob + (size_t)n * HC;
    float v = -1e30f;
    if (c < Cc)
        v = 0.25f * (row[c] + row[c + Cc] + row[c + 2 * Cc] + row[c + 3 * Cc]);
    float mx = v;
#pragma unroll
    for (int o = 1; o < 64; o <<= 1) mx = fmaxf(mx, __shfl_xor(mx, o));
    float ex = (c < Cc) ? expf(v - mx) : 0.f;
    float sm = ex;
#pragma unroll
    for (int o = 1; o < 64; o <<= 1) sm += __shfl_xor(sm, o);
    if (c < Cc) {
        float r = v - mx - logf(sm);
        if (*flag) ((bf16*)out)[(size_t)n * Cc + c] = __float2bfloat16(r);
        else       ((float*)out)[(size_t)n * Cc + c] = r;
    }
}

extern "C" void kernel_launch(void* const* d_in, const int* in_sizes, int n_in,
                              void* d_out, int out_size, void* d_ws, size_t ws_size,
                              hipStream_t stream) {
    (void)in_sizes; (void)n_in; (void)out_size; (void)ws_size;
    const void* x = d_in[0];
    const int* src = (const int*)d_in[1];
    const int* dst = (const int*)d_in[2];

    char* ws = (char*)d_ws;
    size_t off = 0;
    auto alloc = [&](size_t bytes) {
        void* p = ws + off;
        off += (bytes + 255) & ~(size_t)255;
        return p;
    };
    bf16* xb = (bf16*)alloc((size_t)Nn * INF_ * 2);   // 20 MB
    bf16* fs = (bf16*)alloc((size_t)Nn * HC * 2);     // 37.6 MB
    bf16* fd = (bf16*)alloc((size_t)Nn * HC * 2);     // 37.6 MB
    float* Ob = (float*)alloc((size_t)Nn * HC * 4);   // 75.2 MB
    bf16* hb = (bf16*)alloc((size_t)Nn * HD * 2);     // 25.6 MB
    int* ptr = (int*)alloc((Nn + 1) * 4);             // 400 KB
    bf16* wtb = (bf16*)alloc((size_t)WROWS * 128 * 2);// 328 KB
    float* bns = (float*)alloc(2 * HD * 4);
    float* bnss = (float*)alloc(2 * HD * 4);
    bf16* pb = (bf16*)alloc(4096 * 2);
    int* flag = (int*)alloc(256);

    // ---- small-param conversion (biases/attn/bn): d_in idx -> pb arena ----
    static const int spIdx[NSP] = {4, 6, 7, 9, 11, 13, 14, 16, 18, 19, 21, 22, 23, 24, 25};
    static const int spSz[NSP]  = {HD, HD, HD, HD, HD, HD, HD, HC, HC, HC, HC, HD, HD, HD, HD};
    CvtTab tab;
    int tot = 0;
    for (int i = 0; i < NSP; ++i) { tab.src[i] = d_in[spIdx[i]]; tab.off[i] = tot; tot += spSz[i]; }
    tab.off[NSP] = tot;
    const bf16 *bsrc0 = pb + tab.off[0], *bdst0 = pb + tab.off[1], *attn0 = pb + tab.off[2],
               *bres0 = pb + tab.off[3], *bsrc1 = pb + tab.off[4], *bdst1 = pb + tab.off[5],
               *attn1 = pb + tab.off[6], *bsrc2 = pb + tab.off[7], *bdst2 = pb + tab.off[8],
               *attn2 = pb + tab.off[9], *bres2 = pb + tab.off[10],
               *g0 = pb + tab.off[11], *be0 = pb + tab.off[12],
               *g1 = pb + tab.off[13], *be1 = pb + tab.off[14];

    // ---- packed Wt: rows [0,384)=L0(Wsrc0,Wdst0,Wres0), [384,640)=L1(Wsrc1,Wdst1),
    //      [640,1216)=L2(Wsrc2,Wdst2,Wres2 @MP=192), [1216,1280)=zero pad ----
    PrepTab pt;
    static const int wIdx[8] = {3, 5, 8, 10, 12, 15, 17, 20};
    static const int wK[8]   = {INF_, INF_, INF_, HD, HD, HD, HD, HD};
    static const int wM[8]   = {HD, HD, HD, HD, HD, HC, HC, HC};
    static const int wMP[8]  = {128, 128, 128, 128, 128, 192, 192, 192};
    static const int wR0[8]  = {0, 128, 256, 384, 512, 640, 832, 1024};
    for (int i = 0; i < 8; ++i) {
        pt.src[i] = d_in[wIdx[i]]; pt.row0[i] = wR0[i];
        pt.K[i] = wK[i]; pt.M[i] = wM[i]; pt.MP[i] = wMP[i];
    }

    detect_dtype<<<1, 64, 0, stream>>>((const unsigned*)x, flag);
    cvt_x<<<(Nn * INF_ + 255) / 256, 256, 0, stream>>>(x, xb, Nn * INF_, flag);
    cvt_params<<<(tot + 255) / 256, 256, 0, stream>>>(tab, pb, tot, flag);
    prep_all<<<(WROWS * 128 + 255) / 256, 256, 0, stream>>>(pt, wtb, flag);
    build_ptr<<<(Nn + 256) / 256, 256, 0, stream>>>(dst, ptr);

    const int fusedGrid = (Nn + 3) / 4;

    // ---------------- layer 0 ----------------
    gemm_multi<INF_, 128, 3, true><<<dim3(6250, 3), 256, 0, stream>>>(
        xb, wtb, bsrc0, bdst0, bres0, fs, fd, Ob, HD);
    zero_u32<<<1, 256, 0, stream>>>((unsigned*)bns, 2 * HD);
    gat_fused_128<false><<<fusedGrid, 256, 0, stream>>>(fs, fd, src, ptr, attn0, nullptr, Ob);
    relu_stats<<<(Nn + 255) / 256, 128, 0, stream>>>(Ob, hb, bns);
    bn_finalize<<<1, HD, 0, stream>>>(bns, g0, be0, bnss);
    bn_apply<<<(Nn * HD + 255) / 256, 256, 0, stream>>>(hb, bnss);

    // ---------------- layer 1 ----------------
    gemm_multi<HD, 128, 2, false><<<dim3(6250, 2), 256, 0, stream>>>(
        hb, wtb + (size_t)384 * 128, bsrc1, bdst1, nullptr, fs, fd, nullptr, HD);
    zero_u32<<<1, 256, 0, stream>>>((unsigned*)bns, 2 * HD);
    gat_fused_128<true><<<fusedGrid, 256, 0, stream>>>(fs, fd, src, ptr, attn1, hb, Ob);
    relu_stats<<<(Nn + 255) / 256, 128, 0, stream>>>(Ob, hb, bns);
    bn_finalize<<<1, HD, 0, stream>>>(bns, g1, be1, bnss);
    bn_apply<<<(Nn * HD + 255) / 256, 256, 0, stream>>>(hb, bnss);

    // ---------------- layer 2 ----------------
    gemm_multi<HD, 192, 3, true><<<dim3(6250, 5), 256, 0, stream>>>(
        hb, wtb + (size_t)640 * 128, bsrc2, bdst2, bres2, fs, fd, Ob, HC);
    gat_fused_188<<<fusedGrid, 256, 0, stream>>>(fs, fd, src, ptr, attn2, Ob);
    final_out<<<Nn, 64, 0, stream>>>(Ob, d_out, flag);
}

// Round 6
// 892.324 us; speedup vs baseline: 4.7197x; 1.2108x over previous
//
#include <hip/hip_runtime.h>
#include <hip/hip_bf16.h>

#define Nn 100000
#define Ee 1000000
#define INF_ 100
#define Hh 4
#define Dd 32
#define HD 128
#define Cc 47
#define HC 188
#define EPSV 1e-5f
#define SLOPE 0.2f

typedef __hip_bfloat16 bf16;
typedef __attribute__((ext_vector_type(8))) short short8;
typedef __attribute__((ext_vector_type(4))) float f32x4;

__device__ __forceinline__ float tof(bf16 v) { return __bfloat162float(v); }
__device__ __forceinline__ float b2f(unsigned short u) {
    return __uint_as_float((unsigned)u << 16);
}
__device__ __forceinline__ float ldb(const bf16* p) {
    return b2f(*(const unsigned short*)p);
}
__device__ __forceinline__ unsigned short f2u(float v) {
    bf16 t = __float2bfloat16(v);
    return *(unsigned short*)&t;
}

// ---------------- dtype detect: 1 = bf16 buffers, 0 = fp32 buffers ----------------
__global__ void detect_dtype(const unsigned* __restrict__ x, int* __restrict__ flag) {
    if (blockIdx.x == 0 && threadIdx.x == 0) {
        int good = 0;
        for (int i = 0; i < 256; ++i) {
            unsigned lo = x[i] & 0xFFFFu;
            float v = __uint_as_float(lo << 16);
            float a = fabsf(v);
            if (a > 1e-4f && a < 10.f) good++;
        }
        *flag = (good >= 128) ? 1 : 0;
    }
}

__device__ __forceinline__ float ld_any(const void* p, int i, int isbf) {
    return isbf ? tof(((const bf16*)p)[i]) : ((const float*)p)[i];
}

// ---------------- x -> canonical bf16 ----------------
__global__ void cvt_x(const void* __restrict__ in, bf16* __restrict__ out, int n,
                      const int* __restrict__ flag) {
    int i = blockIdx.x * blockDim.x + threadIdx.x;
    if (i >= n) return;
    out[i] = __float2bfloat16(ld_any(in, i, *flag));
}

// ---------------- small params (biases/attn/bn) -> canonical bf16 ----------------
#define NSP 15
struct CvtTab { const void* src[NSP]; int off[NSP + 1]; };

__global__ void cvt_params(CvtTab t, bf16* __restrict__ out, int total,
                           const int* __restrict__ flag) {
    int i = blockIdx.x * blockDim.x + threadIdx.x;
    if (i >= total) return;
    int isbf = *flag;
    int seg = 0;
    while (i >= t.off[seg + 1]) seg++;
    out[i] = __float2bfloat16(ld_any(t.src[seg], i - t.off[seg], isbf));
}

// ---------------- all 8 weight mats -> packed transposed Wt[1280][128] ----------------
#define WROWS 1280
struct PrepTab { const void* src[8]; int row0[8]; int K[8]; int M[8]; int MP[8]; };

__global__ void prep_all(PrepTab t, bf16* __restrict__ wtb, const int* __restrict__ flag) {
    int i = blockIdx.x * blockDim.x + threadIdx.x;
    if (i >= WROWS * 128) return;
    int row = i >> 7, k = i & 127;
    int isbf = *flag;
    float v = 0.f;
#pragma unroll
    for (int q = 0; q < 8; ++q) {
        if (row >= t.row0[q] && row < t.row0[q] + t.MP[q]) {
            int m = row - t.row0[q];
            if (m < t.M[q] && k < t.K[q])
                v = ld_any(t.src[q], k * t.M[q] + m, isbf);
        }
    }
    wtb[i] = __float2bfloat16(v);
}

__global__ void zero_u32(unsigned* __restrict__ p, int n) {
    int i = blockIdx.x * blockDim.x + threadIdx.x;
    if (i < n) p[i] = 0u;
}

// ---------------- CSR build: ptr[n] = lower_bound(dst, n); dst is sorted ----------------
__global__ void build_ptr(const int* __restrict__ dst, int* __restrict__ ptr) {
    int n = blockIdx.x * blockDim.x + threadIdx.x;
    if (n > Nn) return;
    if (n == Nn) { ptr[Nn] = Ee; return; }
    int lo = 0, hi = Ee;
    while (lo < hi) {
        int mid = (lo + hi) >> 1;
        if (dst[mid] < n) lo = mid + 1; else hi = mid;
    }
    ptr[n] = lo;
}

// ---------------- merged MFMA GEMM: NOUT outputs share A; all outputs bf16 ----------
// Wt packed [NOUT*MP(+pad)][128]; block = 16 rows x 128 cols (2 tiles/wave).
// ABN: apply BN scale/shift + relu to A while staging (bnp = [128]sc,[128]sh).
template <int KA, int MP, int NOUT, bool ABN>
__global__ __launch_bounds__(256) void gemm_multi(
    const bf16* __restrict__ A, const bf16* __restrict__ Wt,
    const bf16* __restrict__ b0, const bf16* __restrict__ b1,
    const bf16* __restrict__ b2,
    bf16* __restrict__ o0, bf16* __restrict__ o1, bf16* __restrict__ o2,
    int MR, const float* __restrict__ bnp) {
    __shared__ __align__(16) bf16 Al[16 * 136];
    const int row0 = blockIdx.x * 16;  // N = 6250*16 exactly
    const int tid = threadIdx.x;
    if (KA == 128) {
        int r = tid >> 4, k = (tid & 15) * 8;
        if (!ABN) {
            *(int4*)&Al[r * 136 + k] = *(const int4*)&A[(size_t)(row0 + r) * 128 + k];
        } else {
            short8 av = *(const short8*)&A[(size_t)(row0 + r) * 128 + k];
            bf16 tmp[8];
#pragma unroll
            for (int i = 0; i < 8; ++i) {
                float v = b2f((unsigned short)av[i]);
                v = fmaxf(fmaf(v, bnp[k + i], bnp[128 + k + i]), 0.f);
                tmp[i] = __float2bfloat16(v);
            }
            *(int4*)&Al[r * 136 + k] = *(int4*)tmp;
        }
    } else {
        for (int idx = tid; idx < 16 * 128; idx += 256) {
            int r = idx >> 7, k = idx & 127;
            Al[r * 136 + k] = (k < KA) ? A[(size_t)(row0 + r) * KA + k]
                                       : __float2bfloat16(0.f);
        }
    }
    __syncthreads();
    const int wave = tid >> 6, lane = tid & 63;
    const int n16 = lane & 15, quad = lane >> 4;
    const int gbase = blockIdx.y * 128 + wave * 16 + n16;
    f32x4 acc0 = {0.f, 0.f, 0.f, 0.f}, acc1 = {0.f, 0.f, 0.f, 0.f};
    const bf16* wp0 = Wt + (size_t)gbase * 128 + quad * 8;
    const bf16* wp1 = wp0 + (size_t)64 * 128;
    const bf16* ap = Al + n16 * 136 + quad * 8;
#pragma unroll
    for (int ks = 0; ks < 4; ++ks) {
        short8 af = *(const short8*)(ap + ks * 32);
        acc0 = __builtin_amdgcn_mfma_f32_16x16x32_bf16(af, *(const short8*)(wp0 + ks * 32), acc0, 0, 0, 0);
        acc1 = __builtin_amdgcn_mfma_f32_16x16x32_bf16(af, *(const short8*)(wp1 + ks * 32), acc1, 0, 0, 0);
    }
#pragma unroll
    for (int tt = 0; tt < 2; ++tt) {
        int g = gbase + tt * 64;
        if (g >= NOUT * MP) continue;
        int oi = g / MP, lc = g - oi * MP;
        if (lc >= MR) continue;
        const bf16* bp = (oi == 0) ? b0 : (oi == 1) ? b1 : b2;
        bf16* o = (oi == 0) ? o0 : (oi == 1) ? o1 : o2;
        float bb = tof(bp[lc]);
        const f32x4& a = tt ? acc1 : acc0;
#pragma unroll
        for (int i = 0; i < 4; ++i)
            o[(size_t)(row0 + quad * 4 + i) * MR + lc] = __float2bfloat16(a[i] + bb);
    }
}

// ---------------- fused GATv2 edge kernel, M=128 (layers 0,1) ----------------
// One wave per dst; lane holds cols (2*lane, 2*lane+1), head = lane>>4.
// 2-edge-unrolled online softmax. Epilogue: +residual (RESBN: BN+relu applied
// to resb first), conv relu, write bf16 hout.
template <bool RESBN>
__global__ __launch_bounds__(256) void gat_fused_128(
    const bf16* __restrict__ fs, const bf16* __restrict__ fd,
    const int* __restrict__ srcI, const int* __restrict__ ptr,
    const bf16* __restrict__ attn, const bf16* __restrict__ resb,
    const float* __restrict__ bnp, bf16* __restrict__ hout) {
    const int wave = threadIdx.x >> 6, lane = threadIdx.x & 63;
    const int d = blockIdx.x * 4 + wave;
    if (d >= Nn) return;
    const int c0 = lane * 2;
    ushort2 aq = *(const ushort2*)&attn[c0];
    float a0 = b2f(aq.x), a1 = b2f(aq.y);
    ushort2 dq = *(const ushort2*)&fd[(size_t)d * HD + c0];
    float fd0 = b2f(dq.x), fd1 = b2f(dq.y);
    float m = -INFINITY, l = 0.f, O0 = 0.f, O1 = 0.f;
    int e = ptr[d];
    const int e1 = ptr[d + 1];
    for (; e + 1 < e1; e += 2) {
        int sa = srcI[e], sb = srcI[e + 1];
        ushort2 qa = *(const ushort2*)&fs[(size_t)sa * HD + c0];
        ushort2 qb = *(const ushort2*)&fs[(size_t)sb * HD + c0];
        float fa0 = b2f(qa.x), fa1 = b2f(qa.y);
        float fb0 = b2f(qb.x), fb1 = b2f(qb.y);
        float ta0 = fa0 + fd0; ta0 = fmaxf(ta0, ta0 * SLOPE);
        float ta1 = fa1 + fd1; ta1 = fmaxf(ta1, ta1 * SLOPE);
        float tb0 = fb0 + fd0; tb0 = fmaxf(tb0, tb0 * SLOPE);
        float tb1 = fb1 + fd1; tb1 = fmaxf(tb1, tb1 * SLOPE);
        float pa = fmaf(ta0, a0, ta1 * a1);
        float pb = fmaf(tb0, a0, tb1 * a1);
        pa += __shfl_xor(pa, 1); pb += __shfl_xor(pb, 1);
        pa += __shfl_xor(pa, 2); pb += __shfl_xor(pb, 2);
        pa += __shfl_xor(pa, 4); pb += __shfl_xor(pb, 4);
        pa += __shfl_xor(pa, 8); pb += __shfl_xor(pb, 8);
        float mn = fmaxf(m, fmaxf(pa, pb));
        float sc = __expf(m - mn);
        float ea = __expf(pa - mn), eb = __expf(pb - mn);
        l = fmaf(l, sc, ea + eb);
        O0 = fmaf(O0, sc, fmaf(ea, fa0, eb * fb0));
        O1 = fmaf(O1, sc, fmaf(ea, fa1, eb * fb1));
        m = mn;
    }
    if (e < e1) {
        int s = srcI[e];
        ushort2 fq = *(const ushort2*)&fs[(size_t)s * HD + c0];
        float f0 = b2f(fq.x), f1 = b2f(fq.y);
        float t0 = f0 + fd0; t0 = fmaxf(t0, t0 * SLOPE);
        float t1 = f1 + fd1; t1 = fmaxf(t1, t1 * SLOPE);
        float p = fmaf(t0, a0, t1 * a1);
        p += __shfl_xor(p, 1); p += __shfl_xor(p, 2);
        p += __shfl_xor(p, 4); p += __shfl_xor(p, 8);
        float mn = fmaxf(m, p);
        float sc = __expf(m - mn);
        float pe = __expf(p - mn);
        l = fmaf(l, sc, pe);
        O0 = fmaf(O0, sc, pe * f0);
        O1 = fmaf(O1, sc, pe * f1);
    }
    float inv = l > 0.f ? 1.f / l : 0.f;
    ushort2 rq = *(const ushort2*)&resb[(size_t)d * HD + c0];
    float r0 = b2f(rq.x), r1 = b2f(rq.y);
    if (RESBN) {
        r0 = fmaxf(fmaf(r0, bnp[c0], bnp[HD + c0]), 0.f);
        r1 = fmaxf(fmaf(r1, bnp[c0 + 1], bnp[HD + c0 + 1]), 0.f);
    }
    float v0 = fmaxf(fmaf(O0, inv, r0), 0.f);  // conv activation relu
    float v1 = fmaxf(fmaf(O1, inv, r1), 0.f);
    ushort2 ov; ov.x = f2u(v0); ov.y = f2u(v1);
    *(ushort2*)&hout[(size_t)d * HD + c0] = ov;
}

// ---------------- fused GATv2 edge kernel, M=188 (layer 2) + head-mean
//                  + log_softmax + output write ----------------
// Lane = 16*h + j owns cols h*47 + {j, j+16, j+32 (j<15)}; one head per lane.
__global__ __launch_bounds__(256) void gat_fused_188(
    const bf16* __restrict__ fs, const bf16* __restrict__ fd,
    const int* __restrict__ srcI, const int* __restrict__ ptr,
    const bf16* __restrict__ attn, const bf16* __restrict__ rs,
    void* __restrict__ out, const int* __restrict__ flag) {
    const int wave = threadIdx.x >> 6, lane = threadIdx.x & 63;
    const int d = blockIdx.x * 4 + wave;
    if (d >= Nn) return;
    const int h = lane >> 4, j = lane & 15;
    const int c0 = h * Cc + j;
    const bool has2 = (j < 15);
    float a0 = ldb(&attn[c0]);
    float a1 = ldb(&attn[c0 + 16]);
    float a2 = has2 ? ldb(&attn[c0 + 32]) : 0.f;
    const bf16* fdr = fd + (size_t)d * HC;
    float fd0 = ldb(&fdr[c0]);
    float fd1 = ldb(&fdr[c0 + 16]);
    float fd2 = has2 ? ldb(&fdr[c0 + 32]) : 0.f;
    float m = -INFINITY, l = 0.f, O0 = 0.f, O1 = 0.f, O2 = 0.f;
    int e = ptr[d];
    const int e1 = ptr[d + 1];
    for (; e + 1 < e1; e += 2) {
        int sa = srcI[e], sb = srcI[e + 1];
        const bf16* fra = fs + (size_t)sa * HC;
        const bf16* frb = fs + (size_t)sb * HC;
        float fa0 = ldb(&fra[c0]), fb0 = ldb(&frb[c0]);
        float fa1 = ldb(&fra[c0 + 16]), fb1 = ldb(&frb[c0 + 16]);
        float fa2 = has2 ? ldb(&fra[c0 + 32]) : 0.f;
        float fb2 = has2 ? ldb(&frb[c0 + 32]) : 0.f;
        float ta0 = fa0 + fd0; ta0 = fmaxf(ta0, ta0 * SLOPE);
        float ta1 = fa1 + fd1; ta1 = fmaxf(ta1, ta1 * SLOPE);
        float ta2 = fa2 + fd2; ta2 = fmaxf(ta2, ta2 * SLOPE);
        float tb0 = fb0 + fd0; tb0 = fmaxf(tb0, tb0 * SLOPE);
        float tb1 = fb1 + fd1; tb1 = fmaxf(tb1, tb1 * SLOPE);
        float tb2 = fb2 + fd2; tb2 = fmaxf(tb2, tb2 * SLOPE);
        float pa = fmaf(ta0, a0, fmaf(ta1, a1, ta2 * a2));
        float pb = fmaf(tb0, a0, fmaf(tb1, a1, tb2 * a2));
        pa += __shfl_xor(pa, 1); pb += __shfl_xor(pb, 1);
        pa += __shfl_xor(pa, 2); pb += __shfl_xor(pb, 2);
        pa += __shfl_xor(pa, 4); pb += __shfl_xor(pb, 4);
        pa += __shfl_xor(pa, 8); pb += __shfl_xor(pb, 8);
        float mn = fmaxf(m, fmaxf(pa, pb));
        float sc = __expf(m - mn);
        float ea = __expf(pa - mn), eb = __expf(pb - mn);
        l = fmaf(l, sc, ea + eb);
        O0 = fmaf(O0, sc, fmaf(ea, fa0, eb * fb0));
        O1 = fmaf(O1, sc, fmaf(ea, fa1, eb * fb1));
        O2 = fmaf(O2, sc, fmaf(ea, fa2, eb * fb2));
        m = mn;
    }
    if (e < e1) {
        int s = srcI[e];
        const bf16* fr = fs + (size_t)s * HC;
        float f0 = ldb(&fr[c0]);
        float f1 = ldb(&fr[c0 + 16]);
        float f2 = has2 ? ldb(&fr[c0 + 32]) : 0.f;
        float t0 = f0 + fd0; t0 = fmaxf(t0, t0 * SLOPE);
        float t1 = f1 + fd1; t1 = fmaxf(t1, t1 * SLOPE);
        float t2 = f2 + fd2; t2 = fmaxf(t2, t2 * SLOPE);
        float p = fmaf(t0, a0, fmaf(t1, a1, t2 * a2));
        p += __shfl_xor(p, 1); p += __shfl_xor(p, 2);
        p += __shfl_xor(p, 4); p += __shfl_xor(p, 8);
        float mn = fmaxf(m, p);
        float sc = __expf(m - mn);
        float pe = __expf(p - mn);
        l = fmaf(l, sc, pe);
        O0 = fmaf(O0, sc, pe * f0);
        O1 = fmaf(O1, sc, pe * f1);
        O2 = fmaf(O2, sc, pe * f2);
    }
    // epilogue: +res, head-mean across lane groups, log_softmax, store
    float inv = l > 0.f ? 1.f / l : 0.f;
    const bf16* rr = rs + (size_t)d * HC;
    float v0 = fmaf(O0, inv, ldb(&rr[c0]));
    float v1 = fmaf(O1, inv, ldb(&rr[c0 + 16]));
    float v2 = has2 ? fmaf(O2, inv, ldb(&rr[c0 + 32])) : 0.f;
    v0 += __shfl_xor(v0, 16); v0 += __shfl_xor(v0, 32); v0 *= 0.25f;
    v1 += __shfl_xor(v1, 16); v1 += __shfl_xor(v1, 32); v1 *= 0.25f;
    v2 += __shfl_xor(v2, 16); v2 += __shfl_xor(v2, 32); v2 *= 0.25f;
    float mx = fmaxf(v0, v1);
    if (has2) mx = fmaxf(mx, v2);
    mx = fmaxf(mx, __shfl_xor(mx, 1)); mx = fmaxf(mx, __shfl_xor(mx, 2));
    mx = fmaxf(mx, __shfl_xor(mx, 4)); mx = fmaxf(mx, __shfl_xor(mx, 8));
    float sm = __expf(v0 - mx) + __expf(v1 - mx) + (has2 ? __expf(v2 - mx) : 0.f);
    sm += __shfl_xor(sm, 1); sm += __shfl_xor(sm, 2);
    sm += __shfl_xor(sm, 4); sm += __shfl_xor(sm, 8);
    if (h == 0) {
        float ls = mx + logf(sm);
        if (*flag) {
            bf16* o = (bf16*)out + (size_t)d * Cc;
            o[j] = __float2bfloat16(v0 - ls);
            o[j + 16] = __float2bfloat16(v1 - ls);
            if (has2) o[j + 32] = __float2bfloat16(v2 - ls);
        } else {
            float* o = (float*)out + (size_t)d * Cc;
            o[j] = v0 - ls;
            o[j + 16] = v1 - ls;
            if (has2) o[j + 32] = v2 - ls;
        }
    }
}

// ---------------- per-column BN stats over bf16 h ----------------
__global__ void col_stats(const bf16* __restrict__ in, float* __restrict__ sums) {
    int c = threadIdx.x;  // 128
    int r0 = blockIdx.x * 256;
    int r1 = r0 + 256; if (r1 > Nn) r1 = Nn;
    float s = 0.f, s2 = 0.f;
    for (int r = r0; r < r1; ++r) {
        float v = ldb(&in[(size_t)r * HD + c]);
        s += v; s2 += v * v;
    }
    atomicAdd(&sums[c], s);
    atomicAdd(&sums[HD + c], s2);
}

__global__ void bn_finalize(const float* __restrict__ sums, const bf16* __restrict__ g,
                            const bf16* __restrict__ be, float* __restrict__ ss) {
    int c = threadIdx.x;  // 128
    float mu = sums[c] * (1.f / Nn);
    float var = sums[HD + c] * (1.f / Nn) - mu * mu;
    float sc = tof(g[c]) * rsqrtf(var + EPSV);
    ss[c] = sc;
    ss[HD + c] = tof(be[c]) - mu * sc;
}

extern "C" void kernel_launch(void* const* d_in, const int* in_sizes, int n_in,
                              void* d_out, int out_size, void* d_ws, size_t ws_size,
                              hipStream_t stream) {
    (void)in_sizes; (void)n_in; (void)out_size; (void)ws_size;
    const void* x = d_in[0];
    const int* src = (const int*)d_in[1];
    const int* dst = (const int*)d_in[2];

    char* ws = (char*)d_ws;
    size_t off = 0;
    auto alloc = [&](size_t bytes) {
        void* p = ws + off;
        off += (bytes + 255) & ~(size_t)255;
        return p;
    };
    // rs (37.6 MB) aliases xb+rb (45.6 MB): both dead before L2 GEMM writes rs.
    bf16* xb = (bf16*)alloc((size_t)Nn * INF_ * 2);   // 20 MB
    bf16* rb = (bf16*)alloc((size_t)Nn * HD * 2);     // 25.6 MB
    bf16* rs = xb;                                    // [Nn][HC] alias
    bf16* fs = (bf16*)alloc((size_t)Nn * HC * 2);     // 37.6 MB
    bf16* fd = (bf16*)alloc((size_t)Nn * HC * 2);     // 37.6 MB
    bf16* hbA = (bf16*)alloc((size_t)Nn * HD * 2);    // 25.6 MB
    bf16* hbB = (bf16*)alloc((size_t)Nn * HD * 2);    // 25.6 MB
    int* ptr = (int*)alloc((Nn + 1) * 4);             // 400 KB
    bf16* wtb = (bf16*)alloc((size_t)WROWS * 128 * 2);// 328 KB
    float* bns = (float*)alloc(2 * HD * 4);
    float* bnss0 = (float*)alloc(2 * HD * 4);
    float* bnss1 = (float*)alloc(2 * HD * 4);
    bf16* pb = (bf16*)alloc(4096 * 2);
    int* flag = (int*)alloc(256);

    // ---- small-param conversion (biases/attn/bn): d_in idx -> pb arena ----
    static const int spIdx[NSP] = {4, 6, 7, 9, 11, 13, 14, 16, 18, 19, 21, 22, 23, 24, 25};
    static const int spSz[NSP]  = {HD, HD, HD, HD, HD, HD, HD, HC, HC, HC, HC, HD, HD, HD, HD};
    CvtTab tab;
    int tot = 0;
    for (int i = 0; i < NSP; ++i) { tab.src[i] = d_in[spIdx[i]]; tab.off[i] = tot; tot += spSz[i]; }
    tab.off[NSP] = tot;
    const bf16 *bsrc0 = pb + tab.off[0], *bdst0 = pb + tab.off[1], *attn0 = pb + tab.off[2],
               *bres0 = pb + tab.off[3], *bsrc1 = pb + tab.off[4], *bdst1 = pb + tab.off[5],
               *attn1 = pb + tab.off[6], *bsrc2 = pb + tab.off[7], *bdst2 = pb + tab.off[8],
               *attn2 = pb + tab.off[9], *bres2 = pb + tab.off[10],
               *g0 = pb + tab.off[11], *be0 = pb + tab.off[12],
               *g1 = pb + tab.off[13], *be1 = pb + tab.off[14];

    // ---- packed Wt: rows [0,384)=L0, [384,640)=L1, [640,1216)=L2 @MP=192, pad->1280 ----
    PrepTab pt;
    static const int wIdx[8] = {3, 5, 8, 10, 12, 15, 17, 20};
    static const int wK[8]   = {INF_, INF_, INF_, HD, HD, HD, HD, HD};
    static const int wM[8]   = {HD, HD, HD, HD, HD, HC, HC, HC};
    static const int wMP[8]  = {128, 128, 128, 128, 128, 192, 192, 192};
    static const int wR0[8]  = {0, 128, 256, 384, 512, 640, 832, 1024};
    for (int i = 0; i < 8; ++i) {
        pt.src[i] = d_in[wIdx[i]]; pt.row0[i] = wR0[i];
        pt.K[i] = wK[i]; pt.M[i] = wM[i]; pt.MP[i] = wMP[i];
    }

    detect_dtype<<<1, 64, 0, stream>>>((const unsigned*)x, flag);
    cvt_x<<<(Nn * INF_ + 255) / 256, 256, 0, stream>>>(x, xb, Nn * INF_, flag);
    cvt_params<<<(tot + 255) / 256, 256, 0, stream>>>(tab, pb, tot, flag);
    prep_all<<<(WROWS * 128 + 255) / 256, 256, 0, stream>>>(pt, wtb, flag);
    build_ptr<<<(Nn + 256) / 256, 256, 0, stream>>>(dst, ptr);

    const int fusedGrid = (Nn + 3) / 4;
    const int statsGrid = (Nn + 255) / 256;

    // ---------------- layer 0 ----------------
    gemm_multi<INF_, 128, 3, false><<<dim3(6250, 3), 256, 0, stream>>>(
        xb, wtb, bsrc0, bdst0, bres0, fs, fd, rb, HD, nullptr);
    gat_fused_128<false><<<fusedGrid, 256, 0, stream>>>(fs, fd, src, ptr, attn0,
                                                        rb, nullptr, hbA);
    zero_u32<<<1, 256, 0, stream>>>((unsigned*)bns, 2 * HD);
    col_stats<<<statsGrid, 128, 0, stream>>>(hbA, bns);
    bn_finalize<<<1, HD, 0, stream>>>(bns, g0, be0, bnss0);

    // ---------------- layer 1 ----------------
    gemm_multi<HD, 128, 2, true><<<dim3(6250, 2), 256, 0, stream>>>(
        hbA, wtb + (size_t)384 * 128, bsrc1, bdst1, nullptr, fs, fd, nullptr, HD, bnss0);
    gat_fused_128<true><<<fusedGrid, 256, 0, stream>>>(fs, fd, src, ptr, attn1,
                                                       hbA, bnss0, hbB);
    zero_u32<<<1, 256, 0, stream>>>((unsigned*)bns, 2 * HD);
    col_stats<<<statsGrid, 128, 0, stream>>>(hbB, bns);
    bn_finalize<<<1, HD, 0, stream>>>(bns, g1, be1, bnss1);

    // ---------------- layer 2 ----------------
    gemm_multi<HD, 192, 3, true><<<dim3(6250, 5), 256, 0, stream>>>(
        hbB, wtb + (size_t)640 * 128, bsrc2, bdst2, bres2, fs, fd, rs, HC, bnss1);
    gat_fused_188<<<fusedGrid, 256, 0, stream>>>(fs, fd, src, ptr, attn2, rs,
                                                 d_out, flag);
}

// Round 7
// 744.940 us; speedup vs baseline: 5.6534x; 1.1978x over previous
//
#include <hip/hip_runtime.h>
#include <hip/hip_bf16.h>

#define Nn 100000
#define Ee 1000000
#define INF_ 100
#define Hh 4
#define Dd 32
#define HD 128
#define Cc 47
#define HC 188
#define EPSV 1e-5f
#define SLOPE 0.2f

typedef __hip_bfloat16 bf16;
typedef __attribute__((ext_vector_type(8))) short short8;
typedef __attribute__((ext_vector_type(4))) float f32x4;

__device__ __forceinline__ float tof(bf16 v) { return __bfloat162float(v); }
__device__ __forceinline__ float b2f(unsigned short u) {
    return __uint_as_float((unsigned)u << 16);
}
__device__ __forceinline__ float ldb(const bf16* p) {
    return b2f(*(const unsigned short*)p);
}
__device__ __forceinline__ unsigned short f2u(float v) {
    bf16 t = __float2bfloat16(v);
    return *(unsigned short*)&t;
}

// ---------------- dtype detect: 1 = bf16 buffers, 0 = fp32 buffers ----------------
__global__ void detect_dtype(const unsigned* __restrict__ x, int* __restrict__ flag) {
    if (blockIdx.x == 0 && threadIdx.x == 0) {
        int good = 0;
        for (int i = 0; i < 256; ++i) {
            unsigned lo = x[i] & 0xFFFFu;
            float v = __uint_as_float(lo << 16);
            float a = fabsf(v);
            if (a > 1e-4f && a < 10.f) good++;
        }
        *flag = (good >= 128) ? 1 : 0;
    }
}

__device__ __forceinline__ float ld_any(const void* p, int i, int isbf) {
    return isbf ? tof(((const bf16*)p)[i]) : ((const float*)p)[i];
}

// ---------------- x -> canonical bf16, padded to row stride 128 ----------------
__global__ void cvt_x(const void* __restrict__ in, bf16* __restrict__ out,
                      const int* __restrict__ flag) {
    int i = blockIdx.x * blockDim.x + threadIdx.x;
    if (i >= Nn * 128) return;
    int row = i >> 7, col = i & 127;
    float v = (col < INF_) ? ld_any(in, row * INF_ + col, *flag) : 0.f;
    out[i] = __float2bfloat16(v);
}

// ---------------- small params (biases/attn/bn) -> canonical bf16 ----------------
#define NSP 15
struct CvtTab { const void* src[NSP]; int off[NSP + 1]; };

__global__ void cvt_params(CvtTab t, bf16* __restrict__ out, int total,
                           const int* __restrict__ flag) {
    int i = blockIdx.x * blockDim.x + threadIdx.x;
    if (i >= total) return;
    int isbf = *flag;
    int seg = 0;
    while (i >= t.off[seg + 1]) seg++;
    out[i] = __float2bfloat16(ld_any(t.src[seg], i - t.off[seg], isbf));
}

// ---------------- all 8 weight mats -> packed transposed Wt[1280][128] ----------------
#define WROWS 1280
struct PrepTab { const void* src[8]; int row0[8]; int K[8]; int M[8]; int MP[8]; };

__global__ void prep_all(PrepTab t, bf16* __restrict__ wtb, const int* __restrict__ flag) {
    int i = blockIdx.x * blockDim.x + threadIdx.x;
    if (i >= WROWS * 128) return;
    int row = i >> 7, k = i & 127;
    int isbf = *flag;
    float v = 0.f;
#pragma unroll
    for (int q = 0; q < 8; ++q) {
        if (row >= t.row0[q] && row < t.row0[q] + t.MP[q]) {
            int m = row - t.row0[q];
            if (m < t.M[q] && k < t.K[q])
                v = ld_any(t.src[q], k * t.M[q] + m, isbf);
        }
    }
    wtb[i] = __float2bfloat16(v);
}

__global__ void zero_u32(unsigned* __restrict__ p, int n) {
    int i = blockIdx.x * blockDim.x + threadIdx.x;
    if (i < n) p[i] = 0u;
}

// ---------------- CSR build: ptr[n] = lower_bound(dst, n); dst is sorted ----------------
__global__ void build_ptr(const int* __restrict__ dst, int* __restrict__ ptr) {
    int n = blockIdx.x * blockDim.x + threadIdx.x;
    if (n > Nn) return;
    if (n == Nn) { ptr[Nn] = Ee; return; }
    int lo = 0, hi = Ee;
    while (lo < hi) {
        int mid = (lo + hi) >> 1;
        if (dst[mid] < n) lo = mid + 1; else hi = mid;
    }
    ptr[n] = lo;
}

// ---------------- big-tile MFMA GEMM: 64 rows x (64*CS) cols per block -------------
// A [Nn][128] bf16 staged once in LDS, reused over CS col-subtiles per wave.
// Wt packed [*][128]; col -> (oi, lc) via constant MP. ABN: BN+relu on A staging.
template <int MP, int NOUT, int CS, bool ABN>
__global__ __launch_bounds__(256, 4) void gemm_big(
    const bf16* __restrict__ A, const bf16* __restrict__ Wt,
    const bf16* __restrict__ b0, const bf16* __restrict__ b1,
    const bf16* __restrict__ b2,
    bf16* __restrict__ o0, bf16* __restrict__ o1, bf16* __restrict__ o2,
    int MR, const float* __restrict__ bnp) {
    __shared__ __align__(16) bf16 Al[64 * 136];
    const int row0 = blockIdx.x * 64;
    const int tid = threadIdx.x;
    // stage 64x128 A tile (zero rows past Nn)
#pragma unroll
    for (int j = 0; j < 4; ++j) {
        int idx = tid + j * 256;          // 0..1023 int4 slots
        int r = idx >> 4, kk = (idx & 15) * 8;
        int4 val = {0, 0, 0, 0};
        if (row0 + r < Nn) {
            val = *(const int4*)&A[(size_t)(row0 + r) * 128 + kk];
            if (ABN) {
                short8 av = *(short8*)&val;
                bf16 tmp[8];
#pragma unroll
                for (int u = 0; u < 8; ++u) {
                    float v = b2f((unsigned short)av[u]);
                    v = fmaxf(fmaf(v, bnp[kk + u], bnp[128 + kk + u]), 0.f);
                    tmp[u] = __float2bfloat16(v);
                }
                val = *(int4*)tmp;
            }
        }
        *(int4*)&Al[r * 136 + kk] = val;
    }
    __syncthreads();
    const int wave = tid >> 6, lane = tid & 63;
    const int n16 = lane & 15, quad = lane >> 4;
    const int colbase = blockIdx.y * (64 * CS) + wave * (16 * CS);
    f32x4 acc[4][CS];
#pragma unroll
    for (int rt = 0; rt < 4; ++rt)
#pragma unroll
        for (int c = 0; c < CS; ++c) acc[rt][c] = (f32x4){0.f, 0.f, 0.f, 0.f};
    const bf16* wb[CS];
#pragma unroll
    for (int c = 0; c < CS; ++c)
        wb[c] = Wt + (size_t)(colbase + c * 16 + n16) * 128 + quad * 8;
    const bf16* ap = Al + n16 * 136 + quad * 8;
#pragma unroll
    for (int ks = 0; ks < 4; ++ks) {
        short8 bf[CS];
#pragma unroll
        for (int c = 0; c < CS; ++c) bf[c] = *(const short8*)(wb[c] + ks * 32);
#pragma unroll
        for (int rt = 0; rt < 4; ++rt) {
            short8 af = *(const short8*)(ap + rt * 16 * 136 + ks * 32);
#pragma unroll
            for (int c = 0; c < CS; ++c)
                acc[rt][c] = __builtin_amdgcn_mfma_f32_16x16x32_bf16(af, bf[c], acc[rt][c], 0, 0, 0);
        }
    }
    // epilogue: bias + bf16 store (C/D: col=n16, row=quad*4+reg)
#pragma unroll
    for (int c = 0; c < CS; ++c) {
        int col = colbase + c * 16 + n16;
        int oi = col / MP, lc = col - oi * MP;
        if (oi >= NOUT || lc >= MR) continue;
        const bf16* bp = (oi == 0) ? b0 : (oi == 1) ? b1 : b2;
        bf16* o = (oi == 0) ? o0 : (oi == 1) ? o1 : o2;
        float bb = tof(bp[lc]);
#pragma unroll
        for (int rt = 0; rt < 4; ++rt) {
#pragma unroll
            for (int i = 0; i < 4; ++i) {
                int row = row0 + rt * 16 + quad * 4 + i;
                if (row < Nn)
                    o[(size_t)row * MR + lc] = __float2bfloat16(acc[rt][c][i] + bb);
            }
        }
    }
}

// ---------------- fused GATv2 edge kernel, M=128 (layers 0,1) ----------------
// One wave per dst; lane holds cols (2*lane, 2*lane+1), head = lane>>4.
// 2-edge-unrolled online softmax. Epilogue: +residual (RESBN: BN+relu applied
// to resb first), conv relu, write bf16 hout.
template <bool RESBN>
__global__ __launch_bounds__(256) void gat_fused_128(
    const bf16* __restrict__ fs, const bf16* __restrict__ fd,
    const int* __restrict__ srcI, const int* __restrict__ ptr,
    const bf16* __restrict__ attn, const bf16* __restrict__ resb,
    const float* __restrict__ bnp, bf16* __restrict__ hout) {
    const int wave = threadIdx.x >> 6, lane = threadIdx.x & 63;
    const int d = blockIdx.x * 4 + wave;
    if (d >= Nn) return;
    const int c0 = lane * 2;
    ushort2 aq = *(const ushort2*)&attn[c0];
    float a0 = b2f(aq.x), a1 = b2f(aq.y);
    ushort2 dq = *(const ushort2*)&fd[(size_t)d * HD + c0];
    float fd0 = b2f(dq.x), fd1 = b2f(dq.y);
    float m = -INFINITY, l = 0.f, O0 = 0.f, O1 = 0.f;
    int e = ptr[d];
    const int e1 = ptr[d + 1];
    for (; e + 1 < e1; e += 2) {
        int sa = srcI[e], sb = srcI[e + 1];
        ushort2 qa = *(const ushort2*)&fs[(size_t)sa * HD + c0];
        ushort2 qb = *(const ushort2*)&fs[(size_t)sb * HD + c0];
        float fa0 = b2f(qa.x), fa1 = b2f(qa.y);
        float fb0 = b2f(qb.x), fb1 = b2f(qb.y);
        float ta0 = fa0 + fd0; ta0 = fmaxf(ta0, ta0 * SLOPE);
        float ta1 = fa1 + fd1; ta1 = fmaxf(ta1, ta1 * SLOPE);
        float tb0 = fb0 + fd0; tb0 = fmaxf(tb0, tb0 * SLOPE);
        float tb1 = fb1 + fd1; tb1 = fmaxf(tb1, tb1 * SLOPE);
        float pa = fmaf(ta0, a0, ta1 * a1);
        float pb = fmaf(tb0, a0, tb1 * a1);
        pa += __shfl_xor(pa, 1); pb += __shfl_xor(pb, 1);
        pa += __shfl_xor(pa, 2); pb += __shfl_xor(pb, 2);
        pa += __shfl_xor(pa, 4); pb += __shfl_xor(pb, 4);
        pa += __shfl_xor(pa, 8); pb += __shfl_xor(pb, 8);
        float mn = fmaxf(m, fmaxf(pa, pb));
        float sc = __expf(m - mn);
        float ea = __expf(pa - mn), eb = __expf(pb - mn);
        l = fmaf(l, sc, ea + eb);
        O0 = fmaf(O0, sc, fmaf(ea, fa0, eb * fb0));
        O1 = fmaf(O1, sc, fmaf(ea, fa1, eb * fb1));
        m = mn;
    }
    if (e < e1) {
        int s = srcI[e];
        ushort2 fq = *(const ushort2*)&fs[(size_t)s * HD + c0];
        float f0 = b2f(fq.x), f1 = b2f(fq.y);
        float t0 = f0 + fd0; t0 = fmaxf(t0, t0 * SLOPE);
        float t1 = f1 + fd1; t1 = fmaxf(t1, t1 * SLOPE);
        float p = fmaf(t0, a0, t1 * a1);
        p += __shfl_xor(p, 1); p += __shfl_xor(p, 2);
        p += __shfl_xor(p, 4); p += __shfl_xor(p, 8);
        float mn = fmaxf(m, p);
        float sc = __expf(m - mn);
        float pe = __expf(p - mn);
        l = fmaf(l, sc, pe);
        O0 = fmaf(O0, sc, pe * f0);
        O1 = fmaf(O1, sc, pe * f1);
    }
    float inv = l > 0.f ? 1.f / l : 0.f;
    ushort2 rq = *(const ushort2*)&resb[(size_t)d * HD + c0];
    float r0 = b2f(rq.x), r1 = b2f(rq.y);
    if (RESBN) {
        r0 = fmaxf(fmaf(r0, bnp[c0], bnp[HD + c0]), 0.f);
        r1 = fmaxf(fmaf(r1, bnp[c0 + 1], bnp[HD + c0 + 1]), 0.f);
    }
    float v0 = fmaxf(fmaf(O0, inv, r0), 0.f);  // conv activation relu
    float v1 = fmaxf(fmaf(O1, inv, r1), 0.f);
    ushort2 ov; ov.x = f2u(v0); ov.y = f2u(v1);
    *(ushort2*)&hout[(size_t)d * HD + c0] = ov;
}

// ---------------- fused GATv2 edge kernel, M=188 (layer 2) + head-mean
//                  + log_softmax + output write ----------------
// Lane = 16*h + j owns cols h*47 + {j, j+16, j+32 (j<15)}; one head per lane.
__global__ __launch_bounds__(256) void gat_fused_188(
    const bf16* __restrict__ fs, const bf16* __restrict__ fd,
    const int* __restrict__ srcI, const int* __restrict__ ptr,
    const bf16* __restrict__ attn, const bf16* __restrict__ rs,
    void* __restrict__ out, const int* __restrict__ flag) {
    const int wave = threadIdx.x >> 6, lane = threadIdx.x & 63;
    const int d = blockIdx.x * 4 + wave;
    if (d >= Nn) return;
    const int h = lane >> 4, j = lane & 15;
    const int c0 = h * Cc + j;
    const bool has2 = (j < 15);
    float a0 = ldb(&attn[c0]);
    float a1 = ldb(&attn[c0 + 16]);
    float a2 = has2 ? ldb(&attn[c0 + 32]) : 0.f;
    const bf16* fdr = fd + (size_t)d * HC;
    float fd0 = ldb(&fdr[c0]);
    float fd1 = ldb(&fdr[c0 + 16]);
    float fd2 = has2 ? ldb(&fdr[c0 + 32]) : 0.f;
    float m = -INFINITY, l = 0.f, O0 = 0.f, O1 = 0.f, O2 = 0.f;
    int e = ptr[d];
    const int e1 = ptr[d + 1];
    for (; e + 1 < e1; e += 2) {
        int sa = srcI[e], sb = srcI[e + 1];
        const bf16* fra = fs + (size_t)sa * HC;
        const bf16* frb = fs + (size_t)sb * HC;
        float fa0 = ldb(&fra[c0]), fb0 = ldb(&frb[c0]);
        float fa1 = ldb(&fra[c0 + 16]), fb1 = ldb(&frb[c0 + 16]);
        float fa2 = has2 ? ldb(&fra[c0 + 32]) : 0.f;
        float fb2 = has2 ? ldb(&frb[c0 + 32]) : 0.f;
        float ta0 = fa0 + fd0; ta0 = fmaxf(ta0, ta0 * SLOPE);
        float ta1 = fa1 + fd1; ta1 = fmaxf(ta1, ta1 * SLOPE);
        float ta2 = fa2 + fd2; ta2 = fmaxf(ta2, ta2 * SLOPE);
        float tb0 = fb0 + fd0; tb0 = fmaxf(tb0, tb0 * SLOPE);
        float tb1 = fb1 + fd1; tb1 = fmaxf(tb1, tb1 * SLOPE);
        float tb2 = fb2 + fd2; tb2 = fmaxf(tb2, tb2 * SLOPE);
        float pa = fmaf(ta0, a0, fmaf(ta1, a1, ta2 * a2));
        float pb = fmaf(tb0, a0, fmaf(tb1, a1, tb2 * a2));
        pa += __shfl_xor(pa, 1); pb += __shfl_xor(pb, 1);
        pa += __shfl_xor(pa, 2); pb += __shfl_xor(pb, 2);
        pa += __shfl_xor(pa, 4); pb += __shfl_xor(pb, 4);
        pa += __shfl_xor(pa, 8); pb += __shfl_xor(pb, 8);
        float mn = fmaxf(m, fmaxf(pa, pb));
        float sc = __expf(m - mn);
        float ea = __expf(pa - mn), eb = __expf(pb - mn);
        l = fmaf(l, sc, ea + eb);
        O0 = fmaf(O0, sc, fmaf(ea, fa0, eb * fb0));
        O1 = fmaf(O1, sc, fmaf(ea, fa1, eb * fb1));
        O2 = fmaf(O2, sc, fmaf(ea, fa2, eb * fb2));
        m = mn;
    }
    if (e < e1) {
        int s = srcI[e];
        const bf16* fr = fs + (size_t)s * HC;
        float f0 = ldb(&fr[c0]);
        float f1 = ldb(&fr[c0 + 16]);
        float f2 = has2 ? ldb(&fr[c0 + 32]) : 0.f;
        float t0 = f0 + fd0; t0 = fmaxf(t0, t0 * SLOPE);
        float t1 = f1 + fd1; t1 = fmaxf(t1, t1 * SLOPE);
        float t2 = f2 + fd2; t2 = fmaxf(t2, t2 * SLOPE);
        float p = fmaf(t0, a0, fmaf(t1, a1, t2 * a2));
        p += __shfl_xor(p, 1); p += __shfl_xor(p, 2);
        p += __shfl_xor(p, 4); p += __shfl_xor(p, 8);
        float mn = fmaxf(m, p);
        float sc = __expf(m - mn);
        float pe = __expf(p - mn);
        l = fmaf(l, sc, pe);
        O0 = fmaf(O0, sc, pe * f0);
        O1 = fmaf(O1, sc, pe * f1);
        O2 = fmaf(O2, sc, pe * f2);
    }
    // epilogue: +res, head-mean across lane groups, log_softmax, store
    float inv = l > 0.f ? 1.f / l : 0.f;
    const bf16* rr = rs + (size_t)d * HC;
    float v0 = fmaf(O0, inv, ldb(&rr[c0]));
    float v1 = fmaf(O1, inv, ldb(&rr[c0 + 16]));
    float v2 = has2 ? fmaf(O2, inv, ldb(&rr[c0 + 32])) : 0.f;
    v0 += __shfl_xor(v0, 16); v0 += __shfl_xor(v0, 32); v0 *= 0.25f;
    v1 += __shfl_xor(v1, 16); v1 += __shfl_xor(v1, 32); v1 *= 0.25f;
    v2 += __shfl_xor(v2, 16); v2 += __shfl_xor(v2, 32); v2 *= 0.25f;
    float mx = fmaxf(v0, v1);
    if (has2) mx = fmaxf(mx, v2);
    mx = fmaxf(mx, __shfl_xor(mx, 1)); mx = fmaxf(mx, __shfl_xor(mx, 2));
    mx = fmaxf(mx, __shfl_xor(mx, 4)); mx = fmaxf(mx, __shfl_xor(mx, 8));
    float sm = __expf(v0 - mx) + __expf(v1 - mx) + (has2 ? __expf(v2 - mx) : 0.f);
    sm += __shfl_xor(sm, 1); sm += __shfl_xor(sm, 2);
    sm += __shfl_xor(sm, 4); sm += __shfl_xor(sm, 8);
    if (h == 0) {
        float ls = mx + logf(sm);
        if (*flag) {
            bf16* o = (bf16*)out + (size_t)d * Cc;
            o[j] = __float2bfloat16(v0 - ls);
            o[j + 16] = __float2bfloat16(v1 - ls);
            if (has2) o[j + 32] = __float2bfloat16(v2 - ls);
        } else {
            float* o = (float*)out + (size_t)d * Cc;
            o[j] = v0 - ls;
            o[j + 16] = v1 - ls;
            if (has2) o[j + 32] = v2 - ls;
        }
    }
}

// ---------------- per-column BN stats over bf16 h ----------------
__global__ void col_stats(const bf16* __restrict__ in, float* __restrict__ sums) {
    int c = threadIdx.x;  // 128
    int r0 = blockIdx.x * 256;
    int r1 = r0 + 256; if (r1 > Nn) r1 = Nn;
    float s = 0.f, s2 = 0.f;
    for (int r = r0; r < r1; ++r) {
        float v = ldb(&in[(size_t)r * HD + c]);
        s += v; s2 += v * v;
    }
    atomicAdd(&sums[c], s);
    atomicAdd(&sums[HD + c], s2);
}

__global__ void bn_finalize(const float* __restrict__ sums, const bf16* __restrict__ g,
                            const bf16* __restrict__ be, float* __restrict__ ss) {
    int c = threadIdx.x;  // 128
    float mu = sums[c] * (1.f / Nn);
    float var = sums[HD + c] * (1.f / Nn) - mu * mu;
    float sc = tof(g[c]) * rsqrtf(var + EPSV);
    ss[c] = sc;
    ss[HD + c] = tof(be[c]) - mu * sc;
}

extern "C" void kernel_launch(void* const* d_in, const int* in_sizes, int n_in,
                              void* d_out, int out_size, void* d_ws, size_t ws_size,
                              hipStream_t stream) {
    (void)in_sizes; (void)n_in; (void)out_size; (void)ws_size;
    const void* x = d_in[0];
    const int* src = (const int*)d_in[1];
    const int* dst = (const int*)d_in[2];

    char* ws = (char*)d_ws;
    size_t off = 0;
    auto alloc = [&](size_t bytes) {
        void* p = ws + off;
        off += (bytes + 255) & ~(size_t)255;
        return p;
    };
    // rs (37.6 MB) aliases xb+rb (51.2 MB): both dead before L2 GEMM writes rs.
    bf16* xb = (bf16*)alloc((size_t)Nn * 128 * 2);    // 25.6 MB (stride-128 padded x)
    bf16* rb = (bf16*)alloc((size_t)Nn * HD * 2);     // 25.6 MB
    bf16* rs = xb;                                    // [Nn][HC] alias
    bf16* fs = (bf16*)alloc((size_t)Nn * HC * 2);     // 37.6 MB
    bf16* fd = (bf16*)alloc((size_t)Nn * HC * 2);     // 37.6 MB
    bf16* hbA = (bf16*)alloc((size_t)Nn * HD * 2);    // 25.6 MB
    bf16* hbB = (bf16*)alloc((size_t)Nn * HD * 2);    // 25.6 MB
    int* ptr = (int*)alloc((Nn + 1) * 4);             // 400 KB
    bf16* wtb = (bf16*)alloc((size_t)WROWS * 128 * 2);// 328 KB
    float* bns = (float*)alloc(2 * HD * 4);
    float* bnss0 = (float*)alloc(2 * HD * 4);
    float* bnss1 = (float*)alloc(2 * HD * 4);
    bf16* pb = (bf16*)alloc(4096 * 2);
    int* flag = (int*)alloc(256);

    // ---- small-param conversion (biases/attn/bn): d_in idx -> pb arena ----
    static const int spIdx[NSP] = {4, 6, 7, 9, 11, 13, 14, 16, 18, 19, 21, 22, 23, 24, 25};
    static const int spSz[NSP]  = {HD, HD, HD, HD, HD, HD, HD, HC, HC, HC, HC, HD, HD, HD, HD};
    CvtTab tab;
    int tot = 0;
    for (int i = 0; i < NSP; ++i) { tab.src[i] = d_in[spIdx[i]]; tab.off[i] = tot; tot += spSz[i]; }
    tab.off[NSP] = tot;
    const bf16 *bsrc0 = pb + tab.off[0], *bdst0 = pb + tab.off[1], *attn0 = pb + tab.off[2],
               *bres0 = pb + tab.off[3], *bsrc1 = pb + tab.off[4], *bdst1 = pb + tab.off[5],
               *attn1 = pb + tab.off[6], *bsrc2 = pb + tab.off[7], *bdst2 = pb + tab.off[8],
               *attn2 = pb + tab.off[9], *bres2 = pb + tab.off[10],
               *g0 = pb + tab.off[11], *be0 = pb + tab.off[12],
               *g1 = pb + tab.off[13], *be1 = pb + tab.off[14];

    // ---- packed Wt: rows [0,384)=L0, [384,640)=L1, [640,1216)=L2 @MP=192, pad->1280 ----
    PrepTab pt;
    static const int wIdx[8] = {3, 5, 8, 10, 12, 15, 17, 20};
    static const int wK[8]   = {INF_, INF_, INF_, HD, HD, HD, HD, HD};
    static const int wM[8]   = {HD, HD, HD, HD, HD, HC, HC, HC};
    static const int wMP[8]  = {128, 128, 128, 128, 128, 192, 192, 192};
    static const int wR0[8]  = {0, 128, 256, 384, 512, 640, 832, 1024};
    for (int i = 0; i < 8; ++i) {
        pt.src[i] = d_in[wIdx[i]]; pt.row0[i] = wR0[i];
        pt.K[i] = wK[i]; pt.M[i] = wM[i]; pt.MP[i] = wMP[i];
    }

    detect_dtype<<<1, 64, 0, stream>>>((const unsigned*)x, flag);
    cvt_x<<<(Nn * 128 + 255) / 256, 256, 0, stream>>>(x, xb, flag);
    cvt_params<<<(tot + 255) / 256, 256, 0, stream>>>(tab, pb, tot, flag);
    prep_all<<<(WROWS * 128 + 255) / 256, 256, 0, stream>>>(pt, wtb, flag);
    build_ptr<<<(Nn + 256) / 256, 256, 0, stream>>>(dst, ptr);

    const int fusedGrid = (Nn + 3) / 4;
    const int statsGrid = (Nn + 255) / 256;
    const int rowBlk = (Nn + 63) / 64;  // 1563

    // ---------------- layer 0 ----------------
    gemm_big<128, 3, 2, false><<<dim3(rowBlk, 3), 256, 0, stream>>>(
        xb, wtb, bsrc0, bdst0, bres0, fs, fd, rb, HD, nullptr);
    gat_fused_128<false><<<fusedGrid, 256, 0, stream>>>(fs, fd, src, ptr, attn0,
                                                        rb, nullptr, hbA);
    zero_u32<<<1, 256, 0, stream>>>((unsigned*)bns, 2 * HD);
    col_stats<<<statsGrid, 128, 0, stream>>>(hbA, bns);
    bn_finalize<<<1, HD, 0, stream>>>(bns, g0, be0, bnss0);

    // ---------------- layer 1 ----------------
    gemm_big<128, 2, 2, true><<<dim3(rowBlk, 2), 256, 0, stream>>>(
        hbA, wtb + (size_t)384 * 128, bsrc1, bdst1, nullptr, fs, fd, nullptr, HD, bnss0);
    gat_fused_128<true><<<fusedGrid, 256, 0, stream>>>(fs, fd, src, ptr, attn1,
                                                       hbA, bnss0, hbB);
    zero_u32<<<1, 256, 0, stream>>>((unsigned*)bns, 2 * HD);
    col_stats<<<statsGrid, 128, 0, stream>>>(hbB, bns);
    bn_finalize<<<1, HD, 0, stream>>>(bns, g1, be1, bnss1);

    // ---------------- layer 2 ----------------
    gemm_big<192, 3, 3, true><<<dim3(rowBlk, 3), 256, 0, stream>>>(
        hbB, wtb + (size_t)640 * 128, bsrc2, bdst2, bres2, fs, fd, rs, HC, bnss1);
    gat_fused_188<<<fusedGrid, 256, 0, stream>>>(fs, fd, src, ptr, attn2, rs,
                                                 d_out, flag);
}